// Round 14
// baseline (352.953 us; speedup 1.0000x reference)
//
#include <hip/hip_runtime.h>
#include <math.h>

#define DM     1024
#define RANK   128
#define NCMP   16
#define NKNOW  32768
#define TOPK   8
#define NROWS  4096          // B*S
#define NEG_BIG -3.0e38f
#define TK_SPLIT 32
#define TK_KEYS (NKNOW / TK_SPLIT)   // 1024 keys per split

typedef __attribute__((ext_vector_type(8))) short s8v;    // 8 bf16 (4 VGPRs)
typedef __attribute__((ext_vector_type(4))) float f4v;    // MFMA acc

__device__ __forceinline__ unsigned short f2bf(float f) {
  union { float fl; unsigned u; } v; v.fl = f;
  return (unsigned short)((v.u + 0x7FFFu + ((v.u >> 16) & 1u)) >> 16);  // RNE
}
__device__ __forceinline__ float bf2f(unsigned short u) {
  return __uint_as_float((unsigned)u << 16);
}
__device__ __forceinline__ f4v mfma16(s8v a, s8v b, f4v c) {
  return __builtin_amdgcn_mfma_f32_16x16x32_bf16(a, b, c, 0, 0, 0);
}
// med3: with c <= a invariant, med3(a,b,c) == max(min(a,b),c)  (sorted-insert step)
__device__ __forceinline__ unsigned umed3(unsigned a, unsigned b, unsigned c) {
  unsigned d;
  asm("v_med3_u32 %0, %1, %2, %3" : "=v"(d) : "v"(a), "v"(b), "v"(c));
  return d;
}
// async global->LDS, 16B per lane; LDS dest = wave-uniform base + lane*16
__device__ __forceinline__ void gload16(const unsigned short* g, unsigned short* l) {
  __builtin_amdgcn_global_load_lds(
      (const __attribute__((address_space(1))) unsigned int*)(g),
      (__attribute__((address_space(3))) unsigned int*)(l), 16, 0, 0);
}
#define VMCNT(n) asm volatile("s_waitcnt vmcnt(" #n ")" ::: "memory")
#define BAR() __builtin_amdgcn_s_barrier()

// ---------------- fused LayerNorm + triple router softmax (one block per row) ----------------
__global__ __launch_bounds__(256) void ln_router3_kernel(const float* __restrict__ x,
                                                         const float* __restrict__ g,
                                                         const float* __restrict__ b,
                                                         unsigned short* __restrict__ obf,
                                                         const float* __restrict__ R0,
                                                         const float* __restrict__ R1,
                                                         const float* __restrict__ R2,
                                                         float* __restrict__ w0,
                                                         float* __restrict__ w1,
                                                         float* __restrict__ w2) {
  __shared__ float hs[DM];
  __shared__ float red[3][16][17];
  __shared__ float red1[4], red2[4];
  const int row = blockIdx.x, t = threadIdx.x;
  const float4 v = reinterpret_cast<const float4*>(x + (size_t)row * DM)[t];
  float s = v.x + v.y + v.z + v.w;
#pragma unroll
  for (int m = 1; m <= 32; m <<= 1) s += __shfl_xor(s, m);
  if ((t & 63) == 0) red1[t >> 6] = s;
  __syncthreads();
  const float mu = (red1[0] + red1[1] + red1[2] + red1[3]) * (1.0f / DM);
  const float dx = v.x - mu, dy = v.y - mu, dz = v.z - mu, dw = v.w - mu;
  float ss = dx * dx + dy * dy + dz * dz + dw * dw;
#pragma unroll
  for (int m = 1; m <= 32; m <<= 1) ss += __shfl_xor(ss, m);
  if ((t & 63) == 0) red2[t >> 6] = ss;
  __syncthreads();
  const float var = (red2[0] + red2[1] + red2[2] + red2[3]) * (1.0f / DM);
  const float inv = rsqrtf(var + 1e-5f);
  const float4 g4 = reinterpret_cast<const float4*>(g)[t];
  const float4 b4 = reinterpret_cast<const float4*>(b)[t];
  const float h0 = dx * inv * g4.x + b4.x, h1 = dy * inv * g4.y + b4.y;
  const float h2 = dz * inv * g4.z + b4.z, h3 = dw * inv * g4.w + b4.w;
  reinterpret_cast<ushort4*>(obf + (size_t)row * DM)[t] =
      make_ushort4(f2bf(h0), f2bf(h1), f2bf(h2), f2bf(h3));
  hs[t * 4 + 0] = h0; hs[t * 4 + 1] = h1; hs[t * 4 + 2] = h2; hs[t * 4 + 3] = h3;
  __syncthreads();
  const int o = t & 15, seg = t >> 4;
  float a0 = 0.f, a1 = 0.f, a2 = 0.f;
  for (int d = seg * 64; d < seg * 64 + 64; ++d) {
    const float hv = hs[d];
    a0 += hv * R0[d * NCMP + o];
    a1 += hv * R1[d * NCMP + o];
    a2 += hv * R2[d * NCMP + o];
  }
  red[0][seg][o] = a0; red[1][seg][o] = a1; red[2][seg][o] = a2;
  __syncthreads();
  if (t < 48) {
    const int gg = t >> 4, oo = t & 15;
    float dot = 0.f;
#pragma unroll
    for (int s2 = 0; s2 < 16; ++s2) dot += red[gg][s2][oo];
    float m = dot;
#pragma unroll
    for (int msk = 1; msk < 16; msk <<= 1) m = fmaxf(m, __shfl_xor(m, msk));
    const float e = __expf(dot - m);
    float ssum = e;
#pragma unroll
    for (int msk = 1; msk < 16; msk <<= 1) ssum += __shfl_xor(ssum, msk);
    float* wp = (gg == 0) ? w0 : (gg == 1) ? w1 : w2;
    wp[(size_t)row * NCMP + oo] = e / ssum;
  }
}

// ---------------- fused LayerNorm + single router softmax ----------------
__global__ __launch_bounds__(256) void ln_router1_kernel(const float* __restrict__ x,
                                                         const float* __restrict__ g,
                                                         const float* __restrict__ b,
                                                         unsigned short* __restrict__ obf,
                                                         const float* __restrict__ R,
                                                         float* __restrict__ w) {
  __shared__ float hs[DM];
  __shared__ float red[16][17];
  __shared__ float red1[4], red2[4];
  const int row = blockIdx.x, t = threadIdx.x;
  const float4 v = reinterpret_cast<const float4*>(x + (size_t)row * DM)[t];
  float s = v.x + v.y + v.z + v.w;
#pragma unroll
  for (int m = 1; m <= 32; m <<= 1) s += __shfl_xor(s, m);
  if ((t & 63) == 0) red1[t >> 6] = s;
  __syncthreads();
  const float mu = (red1[0] + red1[1] + red1[2] + red1[3]) * (1.0f / DM);
  const float dx = v.x - mu, dy = v.y - mu, dz = v.z - mu, dw = v.w - mu;
  float ss = dx * dx + dy * dy + dz * dz + dw * dw;
#pragma unroll
  for (int m = 1; m <= 32; m <<= 1) ss += __shfl_xor(ss, m);
  if ((t & 63) == 0) red2[t >> 6] = ss;
  __syncthreads();
  const float var = (red2[0] + red2[1] + red2[2] + red2[3]) * (1.0f / DM);
  const float inv = rsqrtf(var + 1e-5f);
  const float4 g4 = reinterpret_cast<const float4*>(g)[t];
  const float4 b4 = reinterpret_cast<const float4*>(b)[t];
  const float h0 = dx * inv * g4.x + b4.x, h1 = dy * inv * g4.y + b4.y;
  const float h2 = dz * inv * g4.z + b4.z, h3 = dw * inv * g4.w + b4.w;
  reinterpret_cast<ushort4*>(obf + (size_t)row * DM)[t] =
      make_ushort4(f2bf(h0), f2bf(h1), f2bf(h2), f2bf(h3));
  hs[t * 4 + 0] = h0; hs[t * 4 + 1] = h1; hs[t * 4 + 2] = h2; hs[t * 4 + 3] = h3;
  __syncthreads();
  const int o = t & 15, seg = t >> 4;
  float acc = 0.f;
  for (int d = seg * 64; d < seg * 64 + 64; ++d) acc += hs[d] * R[d * NCMP + o];
  red[seg][o] = acc;
  __syncthreads();
  if (t < 16) {
    float dot = 0.f;
#pragma unroll
    for (int s2 = 0; s2 < 16; ++s2) dot += red[s2][t];
    float m = dot;
#pragma unroll
    for (int msk = 1; msk < 16; msk <<= 1) m = fmaxf(m, __shfl_xor(m, msk));
    const float e = __expf(dot - m);
    float ssum = e;
#pragma unroll
    for (int msk = 1; msk < 16; msk <<= 1) ssum += __shfl_xor(ssum, msk);
    w[(size_t)row * NCMP + t] = e / ssum;
  }
}

// ---------------- transpose + bf16 convert body (one 32x32 tile) ----------------
__device__ __forceinline__ void tcvt_body(const float* __restrict__ in,
                                          unsigned short* __restrict__ out,
                                          int K, int N, int bx, int by, int bz, int t) {
  __shared__ float ld[32][33];
  const int k0 = by * 32, n0 = bx * 32;
  const float* ib = in + (size_t)bz * K * N;
  unsigned short* ob = out + (size_t)bz * K * N;
  const int kl = t >> 3, nl = (t & 7) * 4;
  const float4 v = *reinterpret_cast<const float4*>(&ib[(size_t)(k0 + kl) * N + n0 + nl]);
  ld[kl][nl] = v.x; ld[kl][nl + 1] = v.y; ld[kl][nl + 2] = v.z; ld[kl][nl + 3] = v.w;
  __syncthreads();
  const int nw = t >> 3, kw = (t & 7) * 4;
  ushort4 o = make_ushort4(f2bf(ld[kw][nw]), f2bf(ld[kw + 1][nw]),
                           f2bf(ld[kw + 2][nw]), f2bf(ld[kw + 3][nw]));
  *reinterpret_cast<ushort4*>(&ob[(size_t)(n0 + nw) * K + k0 + kw]) = o;
}

// ---------------- single prep kernel: all one-time weight converts ----------------
__global__ __launch_bounds__(256) void prep_kernel(const float* __restrict__ kK,
                                                   unsigned short* __restrict__ kKb,
                                                   const float* __restrict__ neur,
                                                   unsigned short* __restrict__ neurT,
                                                   const float* __restrict__ WQ,
                                                   const float* __restrict__ WK,
                                                   const float* __restrict__ WV,
                                                   unsigned short* __restrict__ WQKVt,
                                                   const float* __restrict__ WO,
                                                   unsigned short* __restrict__ WOt) {
  const int bid = blockIdx.x, t = threadIdx.x;
  if (bid < 2048) {
    const int i = bid * 256 + t;   // 8 elems each
    const float4 a = reinterpret_cast<const float4*>(kK)[2 * i];
    const float4 b = reinterpret_cast<const float4*>(kK)[2 * i + 1];
    reinterpret_cast<ushort4*>(kKb)[2 * i] =
        make_ushort4(f2bf(a.x), f2bf(a.y), f2bf(a.z), f2bf(a.w));
    reinterpret_cast<ushort4*>(kKb)[2 * i + 1] =
        make_ushort4(f2bf(b.x), f2bf(b.y), f2bf(b.z), f2bf(b.w));
  } else if (bid < 4096) {
    const int lb = bid - 2048;
    tcvt_body(neur, neurT, DM, RANK, lb & 3, (lb >> 2) & 31, lb >> 7, t);
  } else if (bid < 4224) {
    const int lb = bid - 4096;
    tcvt_body(WQ, WQKVt, RANK, DM, lb & 31, lb >> 5, 0, t);
  } else if (bid < 4352) {
    const int lb = bid - 4224;
    tcvt_body(WK, WQKVt + (size_t)DM * RANK, RANK, DM, lb & 31, lb >> 5, 0, t);
  } else if (bid < 4480) {
    const int lb = bid - 4352;
    tcvt_body(WV, WQKVt + (size_t)2 * DM * RANK, RANK, DM, lb & 31, lb >> 5, 0, t);
  } else {
    const int lb = bid - 4480;
    tcvt_body(WO, WOt, DM, DM, lb & 31, lb >> 5, 0, t);
  }
}

// ---------------- per-head V transpose (bf16): Vt[bh][d][s] = V[b*1024+s][h*64+d] ----------------
__global__ __launch_bounds__(256) void vtr_kernel(const unsigned short* __restrict__ V,
                                                  unsigned short* __restrict__ Vt) {
  __shared__ unsigned short ld[32][40];
  const int bh = blockIdx.z, b = bh >> 4, hh = bh & 15;
  const int s0 = blockIdx.x * 32, d0 = blockIdx.y * 32;
  const int t = threadIdx.x;
  const int r = t >> 3, c = (t & 7) * 4;
  *reinterpret_cast<ushort4*>(&ld[r][c]) =
      *reinterpret_cast<const ushort4*>(&V[(size_t)(b * 1024 + s0 + r) * DM + hh * 64 + d0 + c]);
  __syncthreads();
  ushort4 o;
  o.x = ld[c + 0][r]; o.y = ld[c + 1][r]; o.z = ld[c + 2][r]; o.w = ld[c + 3][r];
  *reinterpret_cast<ushort4*>(&Vt[((size_t)bh * 64 + d0 + r) * 1024 + s0 + c]) = o;
}

// ---------------- generic NT MFMA GEMM: counted-vmcnt 2-phase (T4), no drain ----------------
template <bool OUT_BF16, bool RES>
__global__ __launch_bounds__(256) void mfma_nt(const unsigned short* __restrict__ A,
                                               const unsigned short* __restrict__ B,
                                               float* __restrict__ Cf,
                                               unsigned short* __restrict__ Cb,
                                               const float* __restrict__ res,
                                               int M, int N, int K, int bshift) {
  __shared__ unsigned short As[2][128 * 64];
  __shared__ unsigned short Bs[2][128 * 64];
  const int t = threadIdx.x;
  const int lane = t & 63, w = t >> 6;
  const int wm = w >> 1, wn = w & 1;
  const int bm = blockIdx.y, bn = blockIdx.x;
  const int l15 = lane & 15, l4 = lane >> 4;
  f4v acc[4][4] = {};
  const int srow = w * 32 + (lane >> 3);
  const int scol = ((lane & 7) ^ (lane >> 3)) * 8;   // pre-swizzled source col (elems)
  const unsigned short* ga = A + (size_t)(bm * 128 + srow) * K + scol;
  const unsigned short* gb = B + (size_t)(bm >> bshift) * ((size_t)N * K) +
                             (size_t)(bn * 128 + srow) * K + scol;
  const int NITER = K >> 6;
#pragma unroll
  for (int j = 0; j < 4; ++j) {
    gload16(ga + (size_t)j * 8 * K, &As[0][w * 2048 + j * 512]);
    gload16(gb + (size_t)j * 8 * K, &Bs[0][w * 2048 + j * 512]);
  }
  for (int it = 0; it < NITER; ++it) {
    const int cur = it & 1;
    if (it + 1 < NITER) {
      const int k0 = (it + 1) * 64;
      unsigned short* const nA = &As[cur ^ 1][w * 2048];
      unsigned short* const nB = &Bs[cur ^ 1][w * 2048];
#pragma unroll
      for (int j = 0; j < 4; ++j) {
        gload16(ga + (size_t)j * 8 * K + k0, nA + j * 512);
        gload16(gb + (size_t)j * 8 * K + k0, nB + j * 512);
      }
      VMCNT(8);           // own tile-it loads landed; next tile's 8 stay in flight
    } else {
      VMCNT(0);
    }
    BAR();                // all waves' tile-it loads landed
#pragma unroll
    for (int ks = 0; ks < 2; ++ks) {
      s8v af[4], bf[4];
      const int sc = (ks * 32 + l4 * 8) ^ ((l15 & 7) * 8);
#pragma unroll
      for (int i = 0; i < 4; ++i) {
        af[i] = *reinterpret_cast<const s8v*>(&As[cur][(wm * 64 + i * 16 + l15) * 64 + sc]);
        bf[i] = *reinterpret_cast<const s8v*>(&Bs[cur][(wn * 64 + i * 16 + l15) * 64 + sc]);
      }
#pragma unroll
      for (int i = 0; i < 4; ++i)
#pragma unroll
        for (int j = 0; j < 4; ++j) acc[i][j] = mfma16(af[i], bf[j], acc[i][j]);
    }
    BAR();                // compute done before buf[cur] is overwritten next iter
  }
#pragma unroll
  for (int i = 0; i < 4; ++i) {
#pragma unroll
    for (int j = 0; j < 4; ++j) {
#pragma unroll
      for (int r = 0; r < 4; ++r) {
        const int row = bm * 128 + wm * 64 + i * 16 + l4 * 4 + r;
        const int col = bn * 128 + wn * 64 + j * 16 + l15;
        float v = acc[i][j][r];
        if constexpr (RES) v += res[(size_t)row * N + col];
        if constexpr (OUT_BF16) Cb[(size_t)row * N + col] = f2bf(v);
        else Cf[(size_t)row * N + col] = v;
      }
    }
  }
}

// ---------------- weighted sum over experts (bf16 ap) -> bf16 outputs ----------------
__global__ __launch_bounds__(128) void wsum_kernel(const unsigned short* __restrict__ ap,
                                                   const float* __restrict__ w0,
                                                   const float* __restrict__ w1,
                                                   const float* __restrict__ w2,
                                                   unsigned short* __restrict__ o0,
                                                   unsigned short* __restrict__ o1,
                                                   unsigned short* __restrict__ o2,
                                                   float scale) {
  const int row = blockIdx.x, r = threadIdx.x;
  float wa[16], wb[16], wc[16];
#pragma unroll
  for (int n = 0; n < 16; ++n) wa[n] = w0[(size_t)row * NCMP + n];
  if (w1) {
#pragma unroll
    for (int n = 0; n < 16; ++n) wb[n] = w1[(size_t)row * NCMP + n];
  }
  if (w2) {
#pragma unroll
    for (int n = 0; n < 16; ++n) wc[n] = w2[(size_t)row * NCMP + n];
  }
  float a0 = 0.f, a1 = 0.f, a2 = 0.f;
  const unsigned short* apr = ap + (size_t)row * (NCMP * RANK) + r;
#pragma unroll
  for (int n = 0; n < 16; ++n) {
    const float v = bf2f(apr[n * RANK]);
    a0 += v * wa[n];
    if (w1) a1 += v * wb[n];
    if (w2) a2 += v * wc[n];
  }
  o0[(size_t)row * RANK + r] = f2bf(a0 * scale);
  if (o1) o1[(size_t)row * RANK + r] = f2bf(a1 * scale);
  if (o2) o2[(size_t)row * RANK + r] = f2bf(a2 * scale);
}

// ---------------- flash attention: frag-major gload_lds, counted vmcnt, causal ----------------
// K/V tiles = 8 lane-linear 512-elem subtiles (subtile s: rows (s>>1)*16+l15, cols
// (s&1)*32+l4*8), double-buffered. Per tile: issue next loads -> VMCNT(4) -> BAR ->
// QK/softmax/PV -> BAR. Never vmcnt(0) in steady state.
__global__ __launch_bounds__(256) void flash_kernel(const unsigned short* __restrict__ Q,
                                                    const unsigned short* __restrict__ K,
                                                    const unsigned short* __restrict__ Vt,
                                                    unsigned short* __restrict__ O) {
  __shared__ unsigned short Qs[8 * 512];
  __shared__ unsigned short Ks[2][8 * 512];
  __shared__ unsigned short Vs[2][8 * 512];
  __shared__ unsigned short Ps[64 * 72];
  const int bh = blockIdx.x, qt = blockIdx.y;
  const int b = bh >> 4, hh = bh & 15;
  const int base = b * 1024, q0 = qt * 64, col = hh * 64;
  const int t = threadIdx.x;
  const int lane = t & 63, w = t >> 6;
  const int l15 = lane & 15, l4 = lane >> 4;
  const unsigned short* Vh = Vt + (size_t)bh * 64 * 1024;   // [d][s]
  // stage Q subtiles s=2w+j, then K0/V0
#pragma unroll
  for (int j = 0; j < 2; ++j)
    gload16(&Q[(size_t)(base + q0 + w * 16 + l15) * DM + col + j * 32 + l4 * 8],
            Qs + (2 * w + j) * 512);
#pragma unroll
  for (int j = 0; j < 2; ++j) {
    gload16(&K[(size_t)(base + w * 16 + l15) * DM + col + j * 32 + l4 * 8],
            Ks[0] + (2 * w + j) * 512);
    gload16(&Vh[(size_t)(w * 16 + l15) * 1024 + j * 32 + l4 * 8],
            Vs[0] + (2 * w + j) * 512);
  }
  float m_r[4], l_r[4];
  f4v o[4] = {};
#pragma unroll
  for (int r = 0; r < 4; ++r) { m_r[r] = NEG_BIG; l_r[r] = 0.f; }
  for (int kt = 0; kt <= qt; ++kt) {
    const int cur = kt & 1;
    if (kt < qt) {
      const int kn = (kt + 1) * 64;
#pragma unroll
      for (int j = 0; j < 2; ++j) {
        gload16(&K[(size_t)(base + kn + w * 16 + l15) * DM + col + j * 32 + l4 * 8],
                Ks[cur ^ 1] + (2 * w + j) * 512);
        gload16(&Vh[(size_t)(w * 16 + l15) * 1024 + kn + j * 32 + l4 * 8],
                Vs[cur ^ 1] + (2 * w + j) * 512);
      }
      VMCNT(4);           // own current-tile loads landed; next tile's 4 in flight
    } else {
      VMCNT(0);
    }
    BAR();                // all waves' current-tile loads landed
    const int k0 = kt * 64;
    f4v s[4] = {};
#pragma unroll
    for (int ks = 0; ks < 2; ++ks) {
      s8v a = *reinterpret_cast<const s8v*>(&Qs[(2 * w + ks) * 512 + lane * 8]);
#pragma unroll
      for (int nj = 0; nj < 4; ++nj) {
        s8v bb = *reinterpret_cast<const s8v*>(&Ks[cur][(2 * nj + ks) * 512 + lane * 8]);
        s[nj] = mfma16(a, bb, s[nj]);
      }
    }
#pragma unroll
    for (int r = 0; r < 4; ++r) {
      const int grow = q0 + w * 16 + l4 * 4 + r;
      float sv[4];
#pragma unroll
      for (int nj = 0; nj < 4; ++nj) {
        const float xx = s[nj][r] * 0.125f;
        const int gcol = k0 + nj * 16 + l15;
        sv[nj] = (gcol <= grow) ? xx : NEG_BIG;
      }
      float mt = fmaxf(fmaxf(sv[0], sv[1]), fmaxf(sv[2], sv[3]));
#pragma unroll
      for (int msk = 1; msk < 16; msk <<= 1) mt = fmaxf(mt, __shfl_xor(mt, msk));
      const float mn = fmaxf(m_r[r], mt);
      const float sc = __expf(m_r[r] - mn);
      m_r[r] = mn;
      float rs = 0.f, pv[4];
#pragma unroll
      for (int nj = 0; nj < 4; ++nj) { pv[nj] = __expf(sv[nj] - mn); rs += pv[nj]; }
#pragma unroll
      for (int msk = 1; msk < 16; msk <<= 1) rs += __shfl_xor(rs, msk);
      l_r[r] = l_r[r] * sc + rs;
#pragma unroll
      for (int nd = 0; nd < 4; ++nd) o[nd][r] *= sc;
      // P rows w*16+l4*4+r consumed only by this same wave -> no barrier needed
#pragma unroll
      for (int nj = 0; nj < 4; ++nj)
        Ps[(w * 16 + l4 * 4 + r) * 72 + nj * 16 + l15] = f2bf(pv[nj]);
    }
#pragma unroll
    for (int ks = 0; ks < 2; ++ks) {
      s8v pa = *reinterpret_cast<const s8v*>(&Ps[(w * 16 + l15) * 72 + ks * 32 + l4 * 8]);
#pragma unroll
      for (int nd = 0; nd < 4; ++nd) {
        s8v vb = *reinterpret_cast<const s8v*>(&Vs[cur][(2 * nd + ks) * 512 + lane * 8]);
        o[nd] = mfma16(pa, vb, o[nd]);
      }
    }
    BAR();                // reads of buf[cur] done before next iter's gloads overwrite it
  }
#pragma unroll
  for (int nd = 0; nd < 4; ++nd)
#pragma unroll
    for (int r = 0; r < 4; ++r) {
      const int grow = base + q0 + w * 16 + l4 * 4 + r;
      O[(size_t)grow * DM + col + nd * 16 + l15] = f2bf(o[nd][r] / l_r[r]);
    }
}

// ---------------- fused kscores MFMA GEMM + branchless in-register per-row top-8 ----------------
// 4-buffer rotation, statically unrolled: ONE raw barrier + counted vmcnt per chunk (no drain).
// Bias-pack (+4 acc init, raw-uint compare), med3 ladder, XCD-clustered 1D grid, setprio (T5).
__global__ __launch_bounds__(256) void topk_kernel(const unsigned short* __restrict__ Qm,
                                                   const unsigned short* __restrict__ kK,
                                                   float* __restrict__ tks,
                                                   int* __restrict__ tki) {
  __shared__ __align__(16) char arena[32768];    // 4 x 8KB frag-major K buffers
  unsigned short* const K0 = (unsigned short*)arena;
  unsigned short* const K1 = (unsigned short*)(arena + 8192);
  unsigned short* const K2 = (unsigned short*)(arena + 16384);
  unsigned short* const K3 = (unsigned short*)(arena + 24576);
  const int id = blockIdx.x;
  const int sp = (id & 7) * 4 + ((id >> 3) & 3);   // XCD id%8 covers 4 sp-slices (2MB, L2-fits)
  const int rb = id >> 5;
  const int r0 = rb * 64, kb0 = sp * TK_KEYS;
  const int t = threadIdx.x;
  const int lane = t & 63, w = t >> 6;
  const int l15 = lane & 15, l4 = lane >> 4;
  s8v qf[4];
#pragma unroll
  for (int ks = 0; ks < 4; ++ks)
    qf[ks] = *reinterpret_cast<const s8v*>(
        &Qm[(size_t)(r0 + w * 16 + l15) * RANK + ks * 32 + l4 * 8]);
  unsigned bs0 = 0u, bs1 = 0u, bs2 = 0u, bs3 = 0u, bs4 = 0u, bs5 = 0u, bs6 = 0u, bs7 = 0u;
  const int s0i = 2 * w, s1i = 2 * w + 1;
  const unsigned short* g0 = kK + (size_t)(kb0 + (s0i >> 2) * 16 + l15) * RANK + (s0i & 3) * 32 + l4 * 8;
  const unsigned short* g1 = kK + (size_t)(kb0 + (s1i >> 2) * 16 + l15) * RANK + (s1i & 3) * 32 + l4 * 8;
  gload16(g0, K0 + s0i * 512);
  gload16(g1, K0 + s1i * 512);

#define TK_STEP(BC, BN, CH)                                                        \
  {                                                                                \
    if ((CH) + 1 < 32) {                                                           \
      const size_t off_ = (size_t)((CH) + 1) * 32 * RANK;                          \
      gload16(g0 + off_, (BN) + s0i * 512);                                        \
      gload16(g1 + off_, (BN) + s1i * 512);                                        \
      VMCNT(2);                                                                    \
    } else {                                                                       \
      VMCNT(0);                                                                    \
    }                                                                              \
    BAR();                                                                         \
    f4v a0_ = f4v{4.f, 4.f, 4.f, 4.f};                                             \
    f4v a1_ = f4v{4.f, 4.f, 4.f, 4.f};                                             \
    __builtin_amdgcn_s_setprio(1);                                                 \
    _Pragma("unroll")                                                              \
    for (int ks_ = 0; ks_ < 4; ++ks_) {                                            \
      a0_ = mfma16(*reinterpret_cast<const s8v*>(&(BC)[ks_ * 512 + lane * 8]),     \
                   qf[ks_], a0_);                                                  \
      a1_ = mfma16(*reinterpret_cast<const s8v*>(&(BC)[(4 + ks_) * 512 + lane * 8]),\
                   qf[ks_], a1_);                                                  \
    }                                                                              \
    __builtin_amdgcn_s_setprio(0);                                                 \
    const unsigned ivb_ = 2047u - (unsigned)((CH) * 32 + l4 * 4);                  \
    _Pragma("unroll")                                                              \
    for (int r_ = 0; r_ < 4; ++r_) {                                               \
      const unsigned u_ = __float_as_uint(a0_[r_]);                                \
      const unsigned pk_ = (u_ & 0xFFFFF800u) | (ivb_ - (unsigned)r_);             \
      bs7 = umed3(bs6, pk_, bs7); bs6 = umed3(bs5, pk_, bs6);                      \
      bs5 = umed3(bs4, pk_, bs5); bs4 = umed3(bs3, pk_, bs4);                      \
      bs3 = umed3(bs2, pk_, bs3); bs2 = umed3(bs1, pk_, bs2);                      \
      bs1 = umed3(bs0, pk_, bs1); bs0 = max(bs0, pk_);                             \
    }                                                                              \
    _Pragma("unroll")                                                              \
    for (int r_ = 0; r_ < 4; ++r_) {                                               \
      const unsigned u_ = __float_as_uint(a1_[r_]);                                \
      const unsigned pk_ = (u_ & 0xFFFFF800u) | (ivb_ - (unsigned)(16 + r_));      \
      bs7 = umed3(bs6, pk_, bs7); bs6 = umed3(bs5, pk_, bs6);                      \
      bs5 = umed3(bs4, pk_, bs5); bs4 = umed3(bs3, pk_, bs4);                      \
      bs3 = umed3(bs2, pk_, bs3); bs2 = umed3(bs1, pk_, bs2);                      \
      bs1 = umed3(bs0, pk_, bs1); bs0 = max(bs0, pk_);                             \
    }                                                                              \
  }

  for (int c4 = 0; c4 < 32; c4 += 4) {
    TK_STEP(K0, K1, c4 + 0);
    TK_STEP(K1, K2, c4 + 1);
    TK_STEP(K2, K3, c4 + 2);
    TK_STEP(K3, K0, c4 + 3);
  }
#undef TK_STEP

  unsigned* const M = (unsigned*)arena;   // [64][33] (overlaps K0/K1; last reads >=2 barriers back)
  const int row = w * 16 + l15;
  {
    unsigned* mp = M + row * 33 + l4 * 8;
    mp[0] = bs0; mp[1] = bs1; mp[2] = bs2; mp[3] = bs3;
    mp[4] = bs4; mp[5] = bs5; mp[6] = bs6; mp[7] = bs7;
  }
  __syncthreads();
  if (t < 64) {
    const unsigned* mr = M + t * 33;
    int h0 = 0, h1 = 0, h2 = 0, h3 = 0;
    const size_t oo = ((size_t)sp * NROWS + r0 + t) * TOPK;
    for (int k = 0; k < TOPK; ++k) {
      const unsigned c0 = (h0 < 8) ? mr[0 + h0] : 0u;
      const unsigned c1 = (h1 < 8) ? mr[8 + h1] : 0u;
      const unsigned c2 = (h2 < 8) ? mr[16 + h2] : 0u;
      const unsigned c3 = (h3 < 8) ? mr[24 + h3] : 0u;
      const unsigned m01 = (c0 >= c1) ? c0 : c1; const int l01 = (c0 >= c1) ? 0 : 1;
      const unsigned m23 = (c2 >= c3) ? c2 : c3; const int l23 = (c2 >= c3) ? 2 : 3;
      const unsigned bst = (m01 >= m23) ? m01 : m23;
      const int bl = (m01 >= m23) ? l01 : l23;
      tks[oo + k] = __uint_as_float(bst & 0xFFFFF800u) - 4.0f;   // un-bias
      tki[oo + k] = kb0 + 2047 - (int)(bst & 0x7FFu);
      h0 += (bl == 0); h1 += (bl == 1); h2 += (bl == 2); h3 += (bl == 3);
    }
  }
}

// ---------------- merge splits (parallel rank-select), softmax, gather, out += mem ----------------
__global__ __launch_bounds__(256) void gather_kernel(const float* __restrict__ tks,
                                                     const int* __restrict__ tki,
                                                     const float* __restrict__ kV,
                                                     float* __restrict__ out) {
  __shared__ float ls[TK_SPLIT * TOPK];
  __shared__ int li[TK_SPLIT * TOPK];
  __shared__ float selv[TOPK];
  __shared__ int seli[TOPK];
  __shared__ float wsel[TOPK];
  const int row = blockIdx.x, t = threadIdx.x;
  if (t < TK_SPLIT * TOPK) {
    const int l = t >> 3, k = t & 7;
    ls[t] = tks[((size_t)l * NROWS + row) * TOPK + k];
    li[t] = tki[((size_t)l * NROWS + row) * TOPK + k];
  }
  __syncthreads();
  if (t < TK_SPLIT * TOPK) {
    const float v = ls[t];
    const int myid = li[t];
    int rank = 0;
    for (int j = 0; j < TK_SPLIT * TOPK; ++j) {
      const float u = ls[j];
      rank += (u > v) || (u == v && li[j] < myid);
    }
    if (rank < TOPK) { selv[rank] = v; seli[rank] = myid; }
  }
  __syncthreads();
  if (t == 0) {
    const float m = selv[0];
    float sum = 0.f, e[TOPK];
#pragma unroll
    for (int k = 0; k < TOPK; ++k) { e[k] = __expf(selv[k] - m); sum += e[k]; }
    const float inv = 1.f / sum;
#pragma unroll
    for (int k = 0; k < TOPK; ++k) wsel[k] = e[k] * inv;
  }
  __syncthreads();
  float4 accv = reinterpret_cast<float4*>(out + (size_t)row * DM)[t];
#pragma unroll
  for (int k = 0; k < TOPK; ++k) {
    const float4 v4 = reinterpret_cast<const float4*>(kV + (size_t)seli[k] * DM)[t];
    const float wk = wsel[k];
    accv.x += wk * v4.x; accv.y += wk * v4.y; accv.z += wk * v4.z; accv.w += wk * v4.w;
  }
  reinterpret_cast<float4*>(out + (size_t)row * DM)[t] = accv;
}

extern "C" void kernel_launch(void* const* d_in, const int* in_sizes, int n_in,
                              void* d_out, int out_size, void* d_ws, size_t ws_size,
                              hipStream_t stream) {
  (void)in_sizes; (void)n_in; (void)out_size; (void)ws_size;
  const float* x    = (const float*)d_in[0];
  const float* neur = (const float*)d_in[2];
  const float* kK   = (const float*)d_in[3];
  const float* kV   = (const float*)d_in[4];
  const float* rQ   = (const float*)d_in[5];
  const float* rK   = (const float*)d_in[6];
  const float* rV   = (const float*)d_in[7];
  const float* rM   = (const float*)d_in[8];
  const float* WQ   = (const float*)d_in[9];
  const float* WK   = (const float*)d_in[10];
  const float* WV   = (const float*)d_in[11];
  const float* WO   = (const float*)d_in[12];
  const float* g1   = (const float*)d_in[13];
  const float* b1   = (const float*)d_in[14];
  const float* g2   = (const float*)d_in[15];
  const float* b2   = (const float*)d_in[16];
  float* out = (float*)d_out;

  char* base = (char*)d_ws;
  auto alloc = [&](size_t bytes) { char* r = base; base += (bytes + 255) & ~(size_t)255; return r; };
  unsigned short* hbf   = (unsigned short*)alloc((size_t)NROWS * DM * 2);   // h bf16; reused attn_bf
  unsigned short* apb   = (unsigned short*)alloc((size_t)3 * NROWS * DM * 2); // ap bf16 / QKV bf16
  unsigned short* neurT = (unsigned short*)alloc((size_t)NCMP * RANK * DM * 2);
  unsigned short* WQKVt = (unsigned short*)alloc((size_t)3 * DM * RANK * 2);
  unsigned short* WOt   = (unsigned short*)alloc((size_t)DM * DM * 2);
  unsigned short* kKb   = (unsigned short*)alloc((size_t)NKNOW * RANK * 2);
  unsigned short* hQKVb = (unsigned short*)alloc((size_t)3 * NROWS * RANK * 2);
  unsigned short* Qmb   = (unsigned short*)alloc((size_t)NROWS * RANK * 2);
  unsigned short* Vtb   = (unsigned short*)alloc((size_t)NROWS * DM * 2);   // V per-head transposed
  float* wQw = (float*)alloc((size_t)NROWS * NCMP * 4);
  float* wKw = (float*)alloc((size_t)NROWS * NCMP * 4);
  float* wVw = (float*)alloc((size_t)NROWS * NCMP * 4);
  float* wMw = (float*)alloc((size_t)NROWS * NCMP * 4);
  float* tks = (float*)alloc((size_t)TK_SPLIT * NROWS * TOPK * 4);
  int*   tki = (int*)alloc((size_t)TK_SPLIT * NROWS * TOPK * 4);
  unsigned short* Qb = apb;                 // [3][4096][1024] bf16 (after wsum consumes ap)
  unsigned short* Kb = Qb + (size_t)NROWS * DM;
  unsigned short* Vb = Kb + (size_t)NROWS * DM;
  unsigned short* attnb = hbf;
  unsigned short* hQb = hQKVb;
  unsigned short* hKb = hQKVb + (size_t)NROWS * RANK;
  unsigned short* hVb = hQKVb + (size_t)2 * NROWS * RANK;

  // one-time weight converts, single launch
  prep_kernel<<<5504, 256, 0, stream>>>(kK, kKb, neur, neurT, WQ, WK, WV, WQKVt, WO, WOt);

  // ---- attention half ----
  ln_router3_kernel<<<NROWS, 256, 0, stream>>>(x, g1, b1, hbf, rQ, rK, rV, wQw, wKw, wVw);
  mfma_nt<true, false><<<dim3(16, 32), 256, 0, stream>>>(hbf, neurT, nullptr, apb, nullptr,
                                                         NROWS, NCMP * RANK, DM, 30);
  wsum_kernel<<<NROWS, 128, 0, stream>>>(apb, wQw, wKw, wVw, hQb, hKb, hVb, 1.0f);
  // batched QKV projection: A=[3*4096][128], B switches every 32 row-tiles
  mfma_nt<true, false><<<dim3(8, 96), 256, 0, stream>>>(hQKVb, WQKVt, nullptr, Qb, nullptr,
                                                        3 * NROWS, DM, RANK, 5);
  vtr_kernel<<<dim3(32, 2, 64), 256, 0, stream>>>(Vb, Vtb);
  flash_kernel<<<dim3(64, 16), 256, 0, stream>>>(Qb, Kb, Vtb, attnb);
  mfma_nt<false, true><<<dim3(8, 32), 256, 0, stream>>>(attnb, WOt, out, nullptr, x,
                                                        NROWS, DM, DM, 30);

  // ---- knowledge-memory half ----
  ln_router1_kernel<<<NROWS, 256, 0, stream>>>(out, g2, b2, hbf, rM, wMw);
  mfma_nt<true, false><<<dim3(16, 32), 256, 0, stream>>>(hbf, neurT, nullptr, apb, nullptr,
                                                         NROWS, NCMP * RANK, DM, 30);
  wsum_kernel<<<NROWS, 128, 0, stream>>>(apb, wMw, nullptr, nullptr, Qmb, nullptr, nullptr,
                                         0.08838834764831845f /* 1/sqrt(128) */);
  topk_kernel<<<2048, 256, 0, stream>>>(Qmb, kKb, tks, tki);
  gather_kernel<<<NROWS, 256, 0, stream>>>(tks, tki, kV, out);
}

// Round 15
// 312.155 us; speedup vs baseline: 1.1307x; 1.1307x over previous
//
#include <hip/hip_runtime.h>
#include <math.h>

#define DM     1024
#define RANK   128
#define NCMP   16
#define NKNOW  32768
#define TOPK   8
#define NROWS  4096          // B*S
#define NEG_BIG -3.0e38f
#define TK_SPLIT 32
#define TK_KEYS (NKNOW / TK_SPLIT)   // 1024 keys per split

typedef __attribute__((ext_vector_type(8))) short s8v;    // 8 bf16 (4 VGPRs)
typedef __attribute__((ext_vector_type(4))) float f4v;    // MFMA acc

__device__ __forceinline__ unsigned short f2bf(float f) {
  union { float fl; unsigned u; } v; v.fl = f;
  return (unsigned short)((v.u + 0x7FFFu + ((v.u >> 16) & 1u)) >> 16);  // RNE
}
__device__ __forceinline__ float bf2f(unsigned short u) {
  return __uint_as_float((unsigned)u << 16);
}
__device__ __forceinline__ f4v mfma16(s8v a, s8v b, f4v c) {
  return __builtin_amdgcn_mfma_f32_16x16x32_bf16(a, b, c, 0, 0, 0);
}
// med3: with c <= a invariant, med3(a,b,c) == max(min(a,b),c)  (sorted-insert step)
__device__ __forceinline__ unsigned umed3(unsigned a, unsigned b, unsigned c) {
  unsigned d;
  asm("v_med3_u32 %0, %1, %2, %3" : "=v"(d) : "v"(a), "v"(b), "v"(c));
  return d;
}
// async global->LDS, 16B per lane; LDS dest = wave-uniform base + lane*16
__device__ __forceinline__ void gload16(const unsigned short* g, unsigned short* l) {
  __builtin_amdgcn_global_load_lds(
      (const __attribute__((address_space(1))) unsigned int*)(g),
      (__attribute__((address_space(3))) unsigned int*)(l), 16, 0, 0);
}
#define VMCNT(n) asm volatile("s_waitcnt vmcnt(" #n ")" ::: "memory")
#define BAR() __builtin_amdgcn_s_barrier()

// ---------------- LayerNorm: writes bf16 only ----------------
__global__ __launch_bounds__(256) void ln_kernel(const float* __restrict__ x,
                                                 const float* __restrict__ g,
                                                 const float* __restrict__ b,
                                                 unsigned short* __restrict__ obf) {
  __shared__ float red1[4], red2[4];
  const int row = blockIdx.x, t = threadIdx.x;
  const float4 v = reinterpret_cast<const float4*>(x + (size_t)row * DM)[t];
  float s = v.x + v.y + v.z + v.w;
#pragma unroll
  for (int m = 1; m <= 32; m <<= 1) s += __shfl_xor(s, m);
  if ((t & 63) == 0) red1[t >> 6] = s;
  __syncthreads();
  const float mu = (red1[0] + red1[1] + red1[2] + red1[3]) * (1.0f / DM);
  const float dx = v.x - mu, dy = v.y - mu, dz = v.z - mu, dw = v.w - mu;
  float ss = dx * dx + dy * dy + dz * dz + dw * dw;
#pragma unroll
  for (int m = 1; m <= 32; m <<= 1) ss += __shfl_xor(ss, m);
  if ((t & 63) == 0) red2[t >> 6] = ss;
  __syncthreads();
  const float var = (red2[0] + red2[1] + red2[2] + red2[3]) * (1.0f / DM);
  const float inv = rsqrtf(var + 1e-5f);
  const float4 g4 = reinterpret_cast<const float4*>(g)[t];
  const float4 b4 = reinterpret_cast<const float4*>(b)[t];
  ushort4 u = make_ushort4(f2bf(dx * inv * g4.x + b4.x), f2bf(dy * inv * g4.y + b4.y),
                           f2bf(dz * inv * g4.z + b4.z), f2bf(dw * inv * g4.w + b4.w));
  reinterpret_cast<ushort4*>(obf + (size_t)row * DM)[t] = u;
}

// ---------------- grouped softmax over router scores: groups of 16 cols ----------------
// scores [NROWS][128]; group g cols g*16..g*16+15. Writes w_g if non-null.
__global__ __launch_bounds__(64) void softmax16_kernel(const float* __restrict__ scores,
                                                       float* __restrict__ w0,
                                                       float* __restrict__ w1,
                                                       float* __restrict__ w2,
                                                       float* __restrict__ w3) {
  const int row = blockIdx.x, t = threadIdx.x;
  const int g = t >> 4, o = t & 15;
  const float v = scores[(size_t)row * 128 + g * 16 + o];
  float m = v;
#pragma unroll
  for (int msk = 1; msk < 16; msk <<= 1) m = fmaxf(m, __shfl_xor(m, msk));
  const float e = __expf(v - m);
  float s = e;
#pragma unroll
  for (int msk = 1; msk < 16; msk <<= 1) s += __shfl_xor(s, msk);
  float* wp = (g == 0) ? w0 : (g == 1) ? w1 : (g == 2) ? w2 : w3;
  if (wp) wp[(size_t)row * NCMP + o] = e / s;
}

// ---------------- transpose + bf16 convert body (one 32x32 tile) ----------------
__device__ __forceinline__ void tcvt_body(const float* __restrict__ in,
                                          unsigned short* __restrict__ out,
                                          int K, int N, int bx, int by, int bz, int t) {
  __shared__ float ld[32][33];
  const int k0 = by * 32, n0 = bx * 32;
  const float* ib = in + (size_t)bz * K * N;
  unsigned short* ob = out + (size_t)bz * K * N;
  const int kl = t >> 3, nl = (t & 7) * 4;
  const float4 v = *reinterpret_cast<const float4*>(&ib[(size_t)(k0 + kl) * N + n0 + nl]);
  ld[kl][nl] = v.x; ld[kl][nl + 1] = v.y; ld[kl][nl + 2] = v.z; ld[kl][nl + 3] = v.w;
  __syncthreads();
  const int nw = t >> 3, kw = (t & 7) * 4;
  ushort4 o = make_ushort4(f2bf(ld[kw][nw]), f2bf(ld[kw + 1][nw]),
                           f2bf(ld[kw + 2][nw]), f2bf(ld[kw + 3][nw]));
  *reinterpret_cast<ushort4*>(&ob[(size_t)(n0 + nw) * K + k0 + kw]) = o;
}

// ---------------- single prep kernel: all one-time weight converts ----------------
// [0,2048) kK | [2048,4096) neurT | [4096,4224) WQ | [4224,4352) WK | [4352,4480) WV
// [4480,5504) WO | [5504,5520) routersT build | [5520,5584) routersT zero tail
__global__ __launch_bounds__(256) void prep_kernel(const float* __restrict__ kK,
                                                   unsigned short* __restrict__ kKb,
                                                   const float* __restrict__ neur,
                                                   unsigned short* __restrict__ neurT,
                                                   const float* __restrict__ WQ,
                                                   const float* __restrict__ WK,
                                                   const float* __restrict__ WV,
                                                   unsigned short* __restrict__ WQKVt,
                                                   const float* __restrict__ WO,
                                                   unsigned short* __restrict__ WOt,
                                                   const float* __restrict__ rQ,
                                                   const float* __restrict__ rK,
                                                   const float* __restrict__ rV,
                                                   const float* __restrict__ rM,
                                                   unsigned short* __restrict__ rTb) {
  const int bid = blockIdx.x, t = threadIdx.x;
  if (bid < 2048) {
    const int i = bid * 256 + t;   // 8 elems each
    const float4 a = reinterpret_cast<const float4*>(kK)[2 * i];
    const float4 b = reinterpret_cast<const float4*>(kK)[2 * i + 1];
    reinterpret_cast<ushort4*>(kKb)[2 * i] =
        make_ushort4(f2bf(a.x), f2bf(a.y), f2bf(a.z), f2bf(a.w));
    reinterpret_cast<ushort4*>(kKb)[2 * i + 1] =
        make_ushort4(f2bf(b.x), f2bf(b.y), f2bf(b.z), f2bf(b.w));
  } else if (bid < 4096) {
    const int lb = bid - 2048;
    tcvt_body(neur, neurT, DM, RANK, lb & 3, (lb >> 2) & 31, lb >> 7, t);
  } else if (bid < 4224) {
    const int lb = bid - 4096;
    tcvt_body(WQ, WQKVt, RANK, DM, lb & 31, lb >> 5, 0, t);
  } else if (bid < 4352) {
    const int lb = bid - 4224;
    tcvt_body(WK, WQKVt + (size_t)DM * RANK, RANK, DM, lb & 31, lb >> 5, 0, t);
  } else if (bid < 4480) {
    const int lb = bid - 4352;
    tcvt_body(WV, WQKVt + (size_t)2 * DM * RANK, RANK, DM, lb & 31, lb >> 5, 0, t);
  } else if (bid < 5504) {
    const int lb = bid - 4480;
    tcvt_body(WO, WOt, DM, DM, lb & 31, lb >> 5, 0, t);
  } else if (bid < 5520) {
    const int lb = bid - 5504;           // m*4 + chunk
    const int m = lb >> 2, chunk = lb & 3;
    const float* Rm = (m == 0) ? rQ : (m == 1) ? rK : (m == 2) ? rV : rM;
    const int d = chunk * 256 + t;
#pragma unroll
    for (int j = 0; j < 16; ++j)
      rTb[(size_t)(m * 16 + j) * DM + d] = f2bf(Rm[d * NCMP + j]);
  } else {
    const int idx = (bid - 5520) * 256 + t;   // zero rows 64..127
    reinterpret_cast<ushort4*>(rTb + (size_t)64 * DM)[idx] = make_ushort4(0, 0, 0, 0);
  }
}

// ---------------- per-head V transpose (bf16): Vt[bh][d][s] = V[b*1024+s][h*64+d] ----------------
__global__ __launch_bounds__(256) void vtr_kernel(const unsigned short* __restrict__ V,
                                                  unsigned short* __restrict__ Vt) {
  __shared__ unsigned short ld[32][40];
  const int bh = blockIdx.z, b = bh >> 4, hh = bh & 15;
  const int s0 = blockIdx.x * 32, d0 = blockIdx.y * 32;
  const int t = threadIdx.x;
  const int r = t >> 3, c = (t & 7) * 4;
  *reinterpret_cast<ushort4*>(&ld[r][c]) =
      *reinterpret_cast<const ushort4*>(&V[(size_t)(b * 1024 + s0 + r) * DM + hh * 64 + d0 + c]);
  __syncthreads();
  ushort4 o;
  o.x = ld[c + 0][r]; o.y = ld[c + 1][r]; o.z = ld[c + 2][r]; o.w = ld[c + 3][r];
  *reinterpret_cast<ushort4*>(&Vt[((size_t)bh * 64 + d0 + r) * 1024 + s0 + c]) = o;
}

// ---------------- generic NT MFMA GEMM: counted-vmcnt 2-phase (T4), no drain ----------------
template <bool OUT_BF16, bool RES>
__global__ __launch_bounds__(256) void mfma_nt(const unsigned short* __restrict__ A,
                                               const unsigned short* __restrict__ B,
                                               float* __restrict__ Cf,
                                               unsigned short* __restrict__ Cb,
                                               const float* __restrict__ res,
                                               int M, int N, int K, int bshift) {
  __shared__ unsigned short As[2][128 * 64];
  __shared__ unsigned short Bs[2][128 * 64];
  const int t = threadIdx.x;
  const int lane = t & 63, w = t >> 6;
  const int wm = w >> 1, wn = w & 1;
  const int bm = blockIdx.y, bn = blockIdx.x;
  const int l15 = lane & 15, l4 = lane >> 4;
  f4v acc[4][4] = {};
  const int srow = w * 32 + (lane >> 3);
  const int scol = ((lane & 7) ^ (lane >> 3)) * 8;   // pre-swizzled source col (elems)
  const unsigned short* ga = A + (size_t)(bm * 128 + srow) * K + scol;
  const unsigned short* gb = B + (size_t)(bm >> bshift) * ((size_t)N * K) +
                             (size_t)(bn * 128 + srow) * K + scol;
  const int NITER = K >> 6;
#pragma unroll
  for (int j = 0; j < 4; ++j) {
    gload16(ga + (size_t)j * 8 * K, &As[0][w * 2048 + j * 512]);
    gload16(gb + (size_t)j * 8 * K, &Bs[0][w * 2048 + j * 512]);
  }
  for (int it = 0; it < NITER; ++it) {
    const int cur = it & 1;
    if (it + 1 < NITER) {
      const int k0 = (it + 1) * 64;
      unsigned short* const nA = &As[cur ^ 1][w * 2048];
      unsigned short* const nB = &Bs[cur ^ 1][w * 2048];
#pragma unroll
      for (int j = 0; j < 4; ++j) {
        gload16(ga + (size_t)j * 8 * K + k0, nA + j * 512);
        gload16(gb + (size_t)j * 8 * K + k0, nB + j * 512);
      }
      VMCNT(8);           // own tile-it loads landed; next tile's 8 stay in flight
    } else {
      VMCNT(0);
    }
    BAR();                // all waves' tile-it loads landed
#pragma unroll
    for (int ks = 0; ks < 2; ++ks) {
      s8v af[4], bf[4];
      const int sc = (ks * 32 + l4 * 8) ^ ((l15 & 7) * 8);
#pragma unroll
      for (int i = 0; i < 4; ++i) {
        af[i] = *reinterpret_cast<const s8v*>(&As[cur][(wm * 64 + i * 16 + l15) * 64 + sc]);
        bf[i] = *reinterpret_cast<const s8v*>(&Bs[cur][(wn * 64 + i * 16 + l15) * 64 + sc]);
      }
#pragma unroll
      for (int i = 0; i < 4; ++i)
#pragma unroll
        for (int j = 0; j < 4; ++j) acc[i][j] = mfma16(af[i], bf[j], acc[i][j]);
    }
    BAR();                // compute done before buf[cur] is overwritten next iter
  }
#pragma unroll
  for (int i = 0; i < 4; ++i) {
#pragma unroll
    for (int j = 0; j < 4; ++j) {
#pragma unroll
      for (int r = 0; r < 4; ++r) {
        const int row = bm * 128 + wm * 64 + i * 16 + l4 * 4 + r;
        const int col = bn * 128 + wn * 64 + j * 16 + l15;
        float v = acc[i][j][r];
        if constexpr (RES) v += res[(size_t)row * N + col];
        if constexpr (OUT_BF16) Cb[(size_t)row * N + col] = f2bf(v);
        else Cf[(size_t)row * N + col] = v;
      }
    }
  }
}

// ---------------- weighted sum over experts (bf16 ap) -> bf16 outputs ----------------
__global__ __launch_bounds__(128) void wsum_kernel(const unsigned short* __restrict__ ap,
                                                   const float* __restrict__ w0,
                                                   const float* __restrict__ w1,
                                                   const float* __restrict__ w2,
                                                   unsigned short* __restrict__ o0,
                                                   unsigned short* __restrict__ o1,
                                                   unsigned short* __restrict__ o2,
                                                   float scale) {
  const int row = blockIdx.x, r = threadIdx.x;
  float wa[16], wb[16], wc[16];
#pragma unroll
  for (int n = 0; n < 16; ++n) wa[n] = w0[(size_t)row * NCMP + n];
  if (w1) {
#pragma unroll
    for (int n = 0; n < 16; ++n) wb[n] = w1[(size_t)row * NCMP + n];
  }
  if (w2) {
#pragma unroll
    for (int n = 0; n < 16; ++n) wc[n] = w2[(size_t)row * NCMP + n];
  }
  float a0 = 0.f, a1 = 0.f, a2 = 0.f;
  const unsigned short* apr = ap + (size_t)row * (NCMP * RANK) + r;
#pragma unroll
  for (int n = 0; n < 16; ++n) {
    const float v = bf2f(apr[n * RANK]);
    a0 += v * wa[n];
    if (w1) a1 += v * wb[n];
    if (w2) a2 += v * wc[n];
  }
  o0[(size_t)row * RANK + r] = f2bf(a0 * scale);
  if (o1) o1[(size_t)row * RANK + r] = f2bf(a1 * scale);
  if (o2) o2[(size_t)row * RANK + r] = f2bf(a2 * scale);
}

// ---------------- flash attention: frag-major gload_lds, counted vmcnt, causal ----------------
__global__ __launch_bounds__(256) void flash_kernel(const unsigned short* __restrict__ Q,
                                                    const unsigned short* __restrict__ K,
                                                    const unsigned short* __restrict__ Vt,
                                                    unsigned short* __restrict__ O) {
  __shared__ unsigned short Qs[8 * 512];
  __shared__ unsigned short Ks[2][8 * 512];
  __shared__ unsigned short Vs[2][8 * 512];
  __shared__ unsigned short Ps[64 * 72];
  const int bh = blockIdx.x, qt = blockIdx.y;
  const int b = bh >> 4, hh = bh & 15;
  const int base = b * 1024, q0 = qt * 64, col = hh * 64;
  const int t = threadIdx.x;
  const int lane = t & 63, w = t >> 6;
  const int l15 = lane & 15, l4 = lane >> 4;
  const unsigned short* Vh = Vt + (size_t)bh * 64 * 1024;   // [d][s]
#pragma unroll
  for (int j = 0; j < 2; ++j)
    gload16(&Q[(size_t)(base + q0 + w * 16 + l15) * DM + col + j * 32 + l4 * 8],
            Qs + (2 * w + j) * 512);
#pragma unroll
  for (int j = 0; j < 2; ++j) {
    gload16(&K[(size_t)(base + w * 16 + l15) * DM + col + j * 32 + l4 * 8],
            Ks[0] + (2 * w + j) * 512);
    gload16(&Vh[(size_t)(w * 16 + l15) * 1024 + j * 32 + l4 * 8],
            Vs[0] + (2 * w + j) * 512);
  }
  float m_r[4], l_r[4];
  f4v o[4] = {};
#pragma unroll
  for (int r = 0; r < 4; ++r) { m_r[r] = NEG_BIG; l_r[r] = 0.f; }
  for (int kt = 0; kt <= qt; ++kt) {
    const int cur = kt & 1;
    if (kt < qt) {
      const int kn = (kt + 1) * 64;
#pragma unroll
      for (int j = 0; j < 2; ++j) {
        gload16(&K[(size_t)(base + kn + w * 16 + l15) * DM + col + j * 32 + l4 * 8],
                Ks[cur ^ 1] + (2 * w + j) * 512);
        gload16(&Vh[(size_t)(w * 16 + l15) * 1024 + kn + j * 32 + l4 * 8],
                Vs[cur ^ 1] + (2 * w + j) * 512);
      }
      VMCNT(4);           // own current-tile loads landed; next tile's 4 in flight
    } else {
      VMCNT(0);
    }
    BAR();                // all waves' current-tile loads landed
    const int k0 = kt * 64;
    f4v s[4] = {};
#pragma unroll
    for (int ks = 0; ks < 2; ++ks) {
      s8v a = *reinterpret_cast<const s8v*>(&Qs[(2 * w + ks) * 512 + lane * 8]);
#pragma unroll
      for (int nj = 0; nj < 4; ++nj) {
        s8v bb = *reinterpret_cast<const s8v*>(&Ks[cur][(2 * nj + ks) * 512 + lane * 8]);
        s[nj] = mfma16(a, bb, s[nj]);
      }
    }
#pragma unroll
    for (int r = 0; r < 4; ++r) {
      const int grow = q0 + w * 16 + l4 * 4 + r;
      float sv[4];
#pragma unroll
      for (int nj = 0; nj < 4; ++nj) {
        const float xx = s[nj][r] * 0.125f;
        const int gcol = k0 + nj * 16 + l15;
        sv[nj] = (gcol <= grow) ? xx : NEG_BIG;
      }
      float mt = fmaxf(fmaxf(sv[0], sv[1]), fmaxf(sv[2], sv[3]));
#pragma unroll
      for (int msk = 1; msk < 16; msk <<= 1) mt = fmaxf(mt, __shfl_xor(mt, msk));
      const float mn = fmaxf(m_r[r], mt);
      const float sc = __expf(m_r[r] - mn);
      m_r[r] = mn;
      float rs = 0.f, pv[4];
#pragma unroll
      for (int nj = 0; nj < 4; ++nj) { pv[nj] = __expf(sv[nj] - mn); rs += pv[nj]; }
#pragma unroll
      for (int msk = 1; msk < 16; msk <<= 1) rs += __shfl_xor(rs, msk);
      l_r[r] = l_r[r] * sc + rs;
#pragma unroll
      for (int nd = 0; nd < 4; ++nd) o[nd][r] *= sc;
#pragma unroll
      for (int nj = 0; nj < 4; ++nj)
        Ps[(w * 16 + l4 * 4 + r) * 72 + nj * 16 + l15] = f2bf(pv[nj]);
    }
#pragma unroll
    for (int ks = 0; ks < 2; ++ks) {
      s8v pa = *reinterpret_cast<const s8v*>(&Ps[(w * 16 + l15) * 72 + ks * 32 + l4 * 8]);
#pragma unroll
      for (int nd = 0; nd < 4; ++nd) {
        s8v vb = *reinterpret_cast<const s8v*>(&Vs[cur][(2 * nd + ks) * 512 + lane * 8]);
        o[nd] = mfma16(pa, vb, o[nd]);
      }
    }
    BAR();                // reads of buf[cur] done before next iter's gloads overwrite it
  }
#pragma unroll
  for (int nd = 0; nd < 4; ++nd)
#pragma unroll
    for (int r = 0; r < 4; ++r) {
      const int grow = base + q0 + w * 16 + l4 * 4 + r;
      O[(size_t)grow * DM + col + nd * 16 + l15] = f2bf(o[nd][r] / l_r[r]);
    }
}

// ---------------- fused kscores MFMA GEMM + branchless in-register per-row top-8 ----------------
__global__ __launch_bounds__(256) void topk_kernel(const unsigned short* __restrict__ Qm,
                                                   const unsigned short* __restrict__ kK,
                                                   float* __restrict__ tks,
                                                   int* __restrict__ tki) {
  __shared__ __align__(16) char arena[32768];    // 4 x 8KB frag-major K buffers
  unsigned short* const K0 = (unsigned short*)arena;
  unsigned short* const K1 = (unsigned short*)(arena + 8192);
  unsigned short* const K2 = (unsigned short*)(arena + 16384);
  unsigned short* const K3 = (unsigned short*)(arena + 24576);
  const int id = blockIdx.x;
  const int sp = (id & 7) * 4 + ((id >> 3) & 3);   // XCD id%8 covers 4 sp-slices (2MB, L2-fits)
  const int rb = id >> 5;
  const int r0 = rb * 64, kb0 = sp * TK_KEYS;
  const int t = threadIdx.x;
  const int lane = t & 63, w = t >> 6;
  const int l15 = lane & 15, l4 = lane >> 4;
  s8v qf[4];
#pragma unroll
  for (int ks = 0; ks < 4; ++ks)
    qf[ks] = *reinterpret_cast<const s8v*>(
        &Qm[(size_t)(r0 + w * 16 + l15) * RANK + ks * 32 + l4 * 8]);
  unsigned bs0 = 0u, bs1 = 0u, bs2 = 0u, bs3 = 0u, bs4 = 0u, bs5 = 0u, bs6 = 0u, bs7 = 0u;
  const int s0i = 2 * w, s1i = 2 * w + 1;
  const unsigned short* g0 = kK + (size_t)(kb0 + (s0i >> 2) * 16 + l15) * RANK + (s0i & 3) * 32 + l4 * 8;
  const unsigned short* g1 = kK + (size_t)(kb0 + (s1i >> 2) * 16 + l15) * RANK + (s1i & 3) * 32 + l4 * 8;
  gload16(g0, K0 + s0i * 512);
  gload16(g1, K0 + s1i * 512);

#define TK_STEP(BC, BN, CH)                                                        \
  {                                                                                \
    if ((CH) + 1 < 32) {                                                           \
      const size_t off_ = (size_t)((CH) + 1) * 32 * RANK;                          \
      gload16(g0 + off_, (BN) + s0i * 512);                                        \
      gload16(g1 + off_, (BN) + s1i * 512);                                        \
      VMCNT(2);                                                                    \
    } else {                                                                       \
      VMCNT(0);                                                                    \
    }                                                                              \
    BAR();                                                                         \
    f4v a0_ = f4v{4.f, 4.f, 4.f, 4.f};                                             \
    f4v a1_ = f4v{4.f, 4.f, 4.f, 4.f};                                             \
    __builtin_amdgcn_s_setprio(1);                                                 \
    _Pragma("unroll")                                                              \
    for (int ks_ = 0; ks_ < 4; ++ks_) {                                            \
      a0_ = mfma16(*reinterpret_cast<const s8v*>(&(BC)[ks_ * 512 + lane * 8]),     \
                   qf[ks_], a0_);                                                  \
      a1_ = mfma16(*reinterpret_cast<const s8v*>(&(BC)[(4 + ks_) * 512 + lane * 8]),\
                   qf[ks_], a1_);                                                  \
    }                                                                              \
    __builtin_amdgcn_s_setprio(0);                                                 \
    const unsigned ivb_ = 2047u - (unsigned)((CH) * 32 + l4 * 4);                  \
    _Pragma("unroll")                                                              \
    for (int r_ = 0; r_ < 4; ++r_) {                                               \
      const unsigned u_ = __float_as_uint(a0_[r_]);                                \
      const unsigned pk_ = (u_ & 0xFFFFF800u) | (ivb_ - (unsigned)r_);             \
      bs7 = umed3(bs6, pk_, bs7); bs6 = umed3(bs5, pk_, bs6);                      \
      bs5 = umed3(bs4, pk_, bs5); bs4 = umed3(bs3, pk_, bs4);                      \
      bs3 = umed3(bs2, pk_, bs3); bs2 = umed3(bs1, pk_, bs2);                      \
      bs1 = umed3(bs0, pk_, bs1); bs0 = max(bs0, pk_);                             \
    }                                                                              \
    _Pragma("unroll")                                                              \
    for (int r_ = 0; r_ < 4; ++r_) {                                               \
      const unsigned u_ = __float_as_uint(a1_[r_]);                                \
      const unsigned pk_ = (u_ & 0xFFFFF800u) | (ivb_ - (unsigned)(16 + r_));      \
      bs7 = umed3(bs6, pk_, bs7); bs6 = umed3(bs5, pk_, bs6);                      \
      bs5 = umed3(bs4, pk_, bs5); bs4 = umed3(bs3, pk_, bs4);                      \
      bs3 = umed3(bs2, pk_, bs3); bs2 = umed3(bs1, pk_, bs2);                      \
      bs1 = umed3(bs0, pk_, bs1); bs0 = max(bs0, pk_);                             \
    }                                                                              \
  }

  for (int c4 = 0; c4 < 32; c4 += 4) {
    TK_STEP(K0, K1, c4 + 0);
    TK_STEP(K1, K2, c4 + 1);
    TK_STEP(K2, K3, c4 + 2);
    TK_STEP(K3, K0, c4 + 3);
  }
#undef TK_STEP

  unsigned* const M = (unsigned*)arena;   // [64][33] (overlaps K0/K1; last reads >=2 barriers back)
  const int row = w * 16 + l15;
  {
    unsigned* mp = M + row * 33 + l4 * 8;
    mp[0] = bs0; mp[1] = bs1; mp[2] = bs2; mp[3] = bs3;
    mp[4] = bs4; mp[5] = bs5; mp[6] = bs6; mp[7] = bs7;
  }
  __syncthreads();
  if (t < 64) {
    const unsigned* mr = M + t * 33;
    int h0 = 0, h1 = 0, h2 = 0, h3 = 0;
    const size_t oo = ((size_t)sp * NROWS + r0 + t) * TOPK;
    for (int k = 0; k < TOPK; ++k) {
      const unsigned c0 = (h0 < 8) ? mr[0 + h0] : 0u;
      const unsigned c1 = (h1 < 8) ? mr[8 + h1] : 0u;
      const unsigned c2 = (h2 < 8) ? mr[16 + h2] : 0u;
      const unsigned c3 = (h3 < 8) ? mr[24 + h3] : 0u;
      const unsigned m01 = (c0 >= c1) ? c0 : c1; const int l01 = (c0 >= c1) ? 0 : 1;
      const unsigned m23 = (c2 >= c3) ? c2 : c3; const int l23 = (c2 >= c3) ? 2 : 3;
      const unsigned bst = (m01 >= m23) ? m01 : m23;
      const int bl = (m01 >= m23) ? l01 : l23;
      tks[oo + k] = __uint_as_float(bst & 0xFFFFF800u) - 4.0f;   // un-bias
      tki[oo + k] = kb0 + 2047 - (int)(bst & 0x7FFu);
      h0 += (bl == 0); h1 += (bl == 1); h2 += (bl == 2); h3 += (bl == 3);
    }
  }
}

// ---------------- merge splits (parallel rank-select), softmax, gather, out += mem ----------------
__global__ __launch_bounds__(256) void gather_kernel(const float* __restrict__ tks,
                                                     const int* __restrict__ tki,
                                                     const float* __restrict__ kV,
                                                     float* __restrict__ out) {
  __shared__ float ls[TK_SPLIT * TOPK];
  __shared__ int li[TK_SPLIT * TOPK];
  __shared__ float selv[TOPK];
  __shared__ int seli[TOPK];
  __shared__ float wsel[TOPK];
  const int row = blockIdx.x, t = threadIdx.x;
  if (t < TK_SPLIT * TOPK) {
    const int l = t >> 3, k = t & 7;
    ls[t] = tks[((size_t)l * NROWS + row) * TOPK + k];
    li[t] = tki[((size_t)l * NROWS + row) * TOPK + k];
  }
  __syncthreads();
  if (t < TK_SPLIT * TOPK) {
    const float v = ls[t];
    const int myid = li[t];
    int rank = 0;
    for (int j = 0; j < TK_SPLIT * TOPK; ++j) {
      const float u = ls[j];
      rank += (u > v) || (u == v && li[j] < myid);
    }
    if (rank < TOPK) { selv[rank] = v; seli[rank] = myid; }
  }
  __syncthreads();
  if (t == 0) {
    const float m = selv[0];
    float sum = 0.f, e[TOPK];
#pragma unroll
    for (int k = 0; k < TOPK; ++k) { e[k] = __expf(selv[k] - m); sum += e[k]; }
    const float inv = 1.f / sum;
#pragma unroll
    for (int k = 0; k < TOPK; ++k) wsel[k] = e[k] * inv;
  }
  __syncthreads();
  float4 accv = reinterpret_cast<float4*>(out + (size_t)row * DM)[t];
#pragma unroll
  for (int k = 0; k < TOPK; ++k) {
    const float4 v4 = reinterpret_cast<const float4*>(kV + (size_t)seli[k] * DM)[t];
    const float wk = wsel[k];
    accv.x += wk * v4.x; accv.y += wk * v4.y; accv.z += wk * v4.z; accv.w += wk * v4.w;
  }
  reinterpret_cast<float4*>(out + (size_t)row * DM)[t] = accv;
}

extern "C" void kernel_launch(void* const* d_in, const int* in_sizes, int n_in,
                              void* d_out, int out_size, void* d_ws, size_t ws_size,
                              hipStream_t stream) {
  (void)in_sizes; (void)n_in; (void)out_size; (void)ws_size;
  const float* x    = (const float*)d_in[0];
  const float* neur = (const float*)d_in[2];
  const float* kK   = (const float*)d_in[3];
  const float* kV   = (const float*)d_in[4];
  const float* rQ   = (const float*)d_in[5];
  const float* rK   = (const float*)d_in[6];
  const float* rV   = (const float*)d_in[7];
  const float* rM   = (const float*)d_in[8];
  const float* WQ   = (const float*)d_in[9];
  const float* WK   = (const float*)d_in[10];
  const float* WV   = (const float*)d_in[11];
  const float* WO   = (const float*)d_in[12];
  const float* g1   = (const float*)d_in[13];
  const float* b1   = (const float*)d_in[14];
  const float* g2   = (const float*)d_in[15];
  const float* b2   = (const float*)d_in[16];
  float* out = (float*)d_out;

  char* base = (char*)d_ws;
  auto alloc = [&](size_t bytes) { char* r = base; base += (bytes + 255) & ~(size_t)255; return r; };
  unsigned short* hbf   = (unsigned short*)alloc((size_t)NROWS * DM * 2);   // h bf16; reused attn_bf
  unsigned short* apb   = (unsigned short*)alloc((size_t)3 * NROWS * DM * 2); // ap bf16 / QKV bf16
  unsigned short* neurT = (unsigned short*)alloc((size_t)NCMP * RANK * DM * 2);
  unsigned short* WQKVt = (unsigned short*)alloc((size_t)3 * DM * RANK * 2);
  unsigned short* WOt   = (unsigned short*)alloc((size_t)DM * DM * 2);
  unsigned short* kKb   = (unsigned short*)alloc((size_t)NKNOW * RANK * 2);
  unsigned short* rTb   = (unsigned short*)alloc((size_t)128 * DM * 2);     // routersT [128][1024]
  unsigned short* hQKVb = (unsigned short*)alloc((size_t)3 * NROWS * RANK * 2);
  unsigned short* Qmb   = (unsigned short*)alloc((size_t)NROWS * RANK * 2);
  unsigned short* Vtb   = (unsigned short*)alloc((size_t)NROWS * DM * 2);   // V per-head transposed
  float* scores = (float*)alloc((size_t)NROWS * 128 * 4);                   // router scores
  float* wQw = (float*)alloc((size_t)NROWS * NCMP * 4);
  float* wKw = (float*)alloc((size_t)NROWS * NCMP * 4);
  float* wVw = (float*)alloc((size_t)NROWS * NCMP * 4);
  float* wMw = (float*)alloc((size_t)NROWS * NCMP * 4);
  float* tks = (float*)alloc((size_t)TK_SPLIT * NROWS * TOPK * 4);
  int*   tki = (int*)alloc((size_t)TK_SPLIT * NROWS * TOPK * 4);
  unsigned short* Qb = apb;                 // [3][4096][1024] bf16 (after wsum consumes ap)
  unsigned short* Kb = Qb + (size_t)NROWS * DM;
  unsigned short* Vb = Kb + (size_t)NROWS * DM;
  unsigned short* attnb = hbf;
  unsigned short* hQb = hQKVb;
  unsigned short* hKb = hQKVb + (size_t)NROWS * RANK;
  unsigned short* hVb = hQKVb + (size_t)2 * NROWS * RANK;

  // one-time weight converts, single launch
  prep_kernel<<<5584, 256, 0, stream>>>(kK, kKb, neur, neurT, WQ, WK, WV, WQKVt, WO, WOt,
                                        rQ, rK, rV, rM, rTb);

  // ---- attention half ----
  ln_kernel<<<NROWS, 256, 0, stream>>>(x, g1, b1, hbf);
  mfma_nt<true, false><<<dim3(16, 32), 256, 0, stream>>>(hbf, neurT, nullptr, apb, nullptr,
                                                         NROWS, NCMP * RANK, DM, 30);
  // router scores via MFMA: scores[4096][128] = h @ routersT^T (groups: rQ,rK,rV,rM,pad)
  mfma_nt<false, false><<<dim3(1, 32), 256, 0, stream>>>(hbf, rTb, scores, nullptr, nullptr,
                                                         NROWS, 128, DM, 30);
  softmax16_kernel<<<NROWS, 64, 0, stream>>>(scores, wQw, wKw, wVw, nullptr);
  wsum_kernel<<<NROWS, 128, 0, stream>>>(apb, wQw, wKw, wVw, hQb, hKb, hVb, 1.0f);
  // batched QKV projection: A=[3*4096][128], B switches every 32 row-tiles
  mfma_nt<true, false><<<dim3(8, 96), 256, 0, stream>>>(hQKVb, WQKVt, nullptr, Qb, nullptr,
                                                        3 * NROWS, DM, RANK, 5);
  vtr_kernel<<<dim3(32, 2, 64), 256, 0, stream>>>(Vb, Vtb);
  flash_kernel<<<dim3(64, 16), 256, 0, stream>>>(Qb, Kb, Vtb, attnb);
  mfma_nt<false, true><<<dim3(8, 32), 256, 0, stream>>>(attnb, WOt, out, nullptr, x,
                                                        NROWS, DM, DM, 30);

  // ---- knowledge-memory half ----
  ln_kernel<<<NROWS, 256, 0, stream>>>(out, g2, b2, hbf);
  mfma_nt<true, false><<<dim3(16, 32), 256, 0, stream>>>(hbf, neurT, nullptr, apb, nullptr,
                                                         NROWS, NCMP * RANK, DM, 30);
  mfma_nt<false, false><<<dim3(1, 32), 256, 0, stream>>>(hbf, rTb, scores, nullptr, nullptr,
                                                         NROWS, 128, DM, 30);
  softmax16_kernel<<<NROWS, 64, 0, stream>>>(scores, nullptr, nullptr, nullptr, wMw);
  wsum_kernel<<<NROWS, 128, 0, stream>>>(apb, wMw, nullptr, nullptr, Qmb, nullptr, nullptr,
                                         0.08838834764831845f /* 1/sqrt(128) */);
  topk_kernel<<<2048, 256, 0, stream>>>(Qmb, kKb, tks, tki);
  gather_kernel<<<NROWS, 256, 0, stream>>>(tks, tki, kV, out);
}

// Round 16
// 308.952 us; speedup vs baseline: 1.1424x; 1.0104x over previous
//
#include <hip/hip_runtime.h>
#include <math.h>

#define DM     1024
#define RANK   128
#define NCMP   16
#define NKNOW  32768
#define TOPK   8
#define NROWS  4096          // B*S
#define NEG_BIG -3.0e38f
#define TK_SPLIT 32
#define TK_KEYS (NKNOW / TK_SPLIT)   // 1024 keys per split

typedef __attribute__((ext_vector_type(8))) short s8v;    // 8 bf16 (4 VGPRs)
typedef __attribute__((ext_vector_type(4))) float f4v;    // MFMA acc

__device__ __forceinline__ unsigned short f2bf(float f) {
  union { float fl; unsigned u; } v; v.fl = f;
  return (unsigned short)((v.u + 0x7FFFu + ((v.u >> 16) & 1u)) >> 16);  // RNE
}
__device__ __forceinline__ float bf2f(unsigned short u) {
  return __uint_as_float((unsigned)u << 16);
}
__device__ __forceinline__ f4v mfma16(s8v a, s8v b, f4v c) {
  return __builtin_amdgcn_mfma_f32_16x16x32_bf16(a, b, c, 0, 0, 0);
}
// med3: with c <= a invariant, med3(a,b,c) == max(min(a,b),c)  (sorted-insert step)
__device__ __forceinline__ unsigned umed3(unsigned a, unsigned b, unsigned c) {
  unsigned d;
  asm("v_med3_u32 %0, %1, %2, %3" : "=v"(d) : "v"(a), "v"(b), "v"(c));
  return d;
}
// async global->LDS, 16B per lane; LDS dest = wave-uniform base + lane*16
__device__ __forceinline__ void gload16(const unsigned short* g, unsigned short* l) {
  __builtin_amdgcn_global_load_lds(
      (const __attribute__((address_space(1))) unsigned int*)(g),
      (__attribute__((address_space(3))) unsigned int*)(l), 16, 0, 0);
}
#define VMCNT(n) asm volatile("s_waitcnt vmcnt(" #n ")" ::: "memory")
#define BAR() __builtin_amdgcn_s_barrier()

// ---------------- LayerNorm: writes bf16 only ----------------
__global__ __launch_bounds__(256) void ln_kernel(const float* __restrict__ x,
                                                 const float* __restrict__ g,
                                                 const float* __restrict__ b,
                                                 unsigned short* __restrict__ obf) {
  __shared__ float red1[4], red2[4];
  const int row = blockIdx.x, t = threadIdx.x;
  const float4 v = reinterpret_cast<const float4*>(x + (size_t)row * DM)[t];
  float s = v.x + v.y + v.z + v.w;
#pragma unroll
  for (int m = 1; m <= 32; m <<= 1) s += __shfl_xor(s, m);
  if ((t & 63) == 0) red1[t >> 6] = s;
  __syncthreads();
  const float mu = (red1[0] + red1[1] + red1[2] + red1[3]) * (1.0f / DM);
  const float dx = v.x - mu, dy = v.y - mu, dz = v.z - mu, dw = v.w - mu;
  float ss = dx * dx + dy * dy + dz * dz + dw * dw;
#pragma unroll
  for (int m = 1; m <= 32; m <<= 1) ss += __shfl_xor(ss, m);
  if ((t & 63) == 0) red2[t >> 6] = ss;
  __syncthreads();
  const float var = (red2[0] + red2[1] + red2[2] + red2[3]) * (1.0f / DM);
  const float inv = rsqrtf(var + 1e-5f);
  const float4 g4 = reinterpret_cast<const float4*>(g)[t];
  const float4 b4 = reinterpret_cast<const float4*>(b)[t];
  ushort4 u = make_ushort4(f2bf(dx * inv * g4.x + b4.x), f2bf(dy * inv * g4.y + b4.y),
                           f2bf(dz * inv * g4.z + b4.z), f2bf(dw * inv * g4.w + b4.w));
  reinterpret_cast<ushort4*>(obf + (size_t)row * DM)[t] = u;
}

// ---------------- grouped softmax over router scores: groups of 16 cols ----------------
__global__ __launch_bounds__(64) void softmax16_kernel(const float* __restrict__ scores,
                                                       float* __restrict__ w0,
                                                       float* __restrict__ w1,
                                                       float* __restrict__ w2,
                                                       float* __restrict__ w3) {
  const int row = blockIdx.x, t = threadIdx.x;
  const int g = t >> 4, o = t & 15;
  const float v = scores[(size_t)row * 128 + g * 16 + o];
  float m = v;
#pragma unroll
  for (int msk = 1; msk < 16; msk <<= 1) m = fmaxf(m, __shfl_xor(m, msk));
  const float e = __expf(v - m);
  float s = e;
#pragma unroll
  for (int msk = 1; msk < 16; msk <<= 1) s += __shfl_xor(s, msk);
  float* wp = (g == 0) ? w0 : (g == 1) ? w1 : (g == 2) ? w2 : w3;
  if (wp) wp[(size_t)row * NCMP + o] = e / s;
}

// ---------------- transpose + bf16 convert body (one 32x32 tile) ----------------
__device__ __forceinline__ void tcvt_body(const float* __restrict__ in,
                                          unsigned short* __restrict__ out,
                                          int K, int N, int bx, int by, int bz, int t) {
  __shared__ float ld[32][33];
  const int k0 = by * 32, n0 = bx * 32;
  const float* ib = in + (size_t)bz * K * N;
  unsigned short* ob = out + (size_t)bz * K * N;
  const int kl = t >> 3, nl = (t & 7) * 4;
  const float4 v = *reinterpret_cast<const float4*>(&ib[(size_t)(k0 + kl) * N + n0 + nl]);
  ld[kl][nl] = v.x; ld[kl][nl + 1] = v.y; ld[kl][nl + 2] = v.z; ld[kl][nl + 3] = v.w;
  __syncthreads();
  const int nw = t >> 3, kw = (t & 7) * 4;
  ushort4 o = make_ushort4(f2bf(ld[kw][nw]), f2bf(ld[kw + 1][nw]),
                           f2bf(ld[kw + 2][nw]), f2bf(ld[kw + 3][nw]));
  *reinterpret_cast<ushort4*>(&ob[(size_t)(n0 + nw) * K + k0 + kw]) = o;
}

// ---------------- single prep kernel: all one-time weight converts ----------------
__global__ __launch_bounds__(256) void prep_kernel(const float* __restrict__ kK,
                                                   unsigned short* __restrict__ kKb,
                                                   const float* __restrict__ neur,
                                                   unsigned short* __restrict__ neurT,
                                                   const float* __restrict__ WQ,
                                                   const float* __restrict__ WK,
                                                   const float* __restrict__ WV,
                                                   unsigned short* __restrict__ WQKVt,
                                                   const float* __restrict__ WO,
                                                   unsigned short* __restrict__ WOt,
                                                   const float* __restrict__ rQ,
                                                   const float* __restrict__ rK,
                                                   const float* __restrict__ rV,
                                                   const float* __restrict__ rM,
                                                   unsigned short* __restrict__ rTb) {
  const int bid = blockIdx.x, t = threadIdx.x;
  if (bid < 2048) {
    const int i = bid * 256 + t;   // 8 elems each
    const float4 a = reinterpret_cast<const float4*>(kK)[2 * i];
    const float4 b = reinterpret_cast<const float4*>(kK)[2 * i + 1];
    reinterpret_cast<ushort4*>(kKb)[2 * i] =
        make_ushort4(f2bf(a.x), f2bf(a.y), f2bf(a.z), f2bf(a.w));
    reinterpret_cast<ushort4*>(kKb)[2 * i + 1] =
        make_ushort4(f2bf(b.x), f2bf(b.y), f2bf(b.z), f2bf(b.w));
  } else if (bid < 4096) {
    const int lb = bid - 2048;
    tcvt_body(neur, neurT, DM, RANK, lb & 3, (lb >> 2) & 31, lb >> 7, t);
  } else if (bid < 4224) {
    const int lb = bid - 4096;
    tcvt_body(WQ, WQKVt, RANK, DM, lb & 31, lb >> 5, 0, t);
  } else if (bid < 4352) {
    const int lb = bid - 4224;
    tcvt_body(WK, WQKVt + (size_t)DM * RANK, RANK, DM, lb & 31, lb >> 5, 0, t);
  } else if (bid < 4480) {
    const int lb = bid - 4352;
    tcvt_body(WV, WQKVt + (size_t)2 * DM * RANK, RANK, DM, lb & 31, lb >> 5, 0, t);
  } else if (bid < 5504) {
    const int lb = bid - 4480;
    tcvt_body(WO, WOt, DM, DM, lb & 31, lb >> 5, 0, t);
  } else if (bid < 5520) {
    const int lb = bid - 5504;           // m*4 + chunk
    const int m = lb >> 2, chunk = lb & 3;
    const float* Rm = (m == 0) ? rQ : (m == 1) ? rK : (m == 2) ? rV : rM;
    const int d = chunk * 256 + t;
#pragma unroll
    for (int j = 0; j < 16; ++j)
      rTb[(size_t)(m * 16 + j) * DM + d] = f2bf(Rm[d * NCMP + j]);
  } else {
    const int idx = (bid - 5520) * 256 + t;   // zero rows 64..127
    reinterpret_cast<ushort4*>(rTb + (size_t)64 * DM)[idx] = make_ushort4(0, 0, 0, 0);
  }
}

// ---------------- per-head V transpose (bf16): Vt[bh][d][s] = V[b*1024+s][h*64+d] ----------------
__global__ __launch_bounds__(256) void vtr_kernel(const unsigned short* __restrict__ V,
                                                  unsigned short* __restrict__ Vt) {
  __shared__ unsigned short ld[32][40];
  const int bh = blockIdx.z, b = bh >> 4, hh = bh & 15;
  const int s0 = blockIdx.x * 32, d0 = blockIdx.y * 32;
  const int t = threadIdx.x;
  const int r = t >> 3, c = (t & 7) * 4;
  *reinterpret_cast<ushort4*>(&ld[r][c]) =
      *reinterpret_cast<const ushort4*>(&V[(size_t)(b * 1024 + s0 + r) * DM + hh * 64 + d0 + c]);
  __syncthreads();
  ushort4 o;
  o.x = ld[c + 0][r]; o.y = ld[c + 1][r]; o.z = ld[c + 2][r]; o.w = ld[c + 3][r];
  *reinterpret_cast<ushort4*>(&Vt[((size_t)bh * 64 + d0 + r) * 1024 + s0 + c]) = o;
}

// ---------------- generic NT MFMA GEMM: counted-vmcnt 2-phase, XCD-clustered 1D grid ----------------
// Grid 1D NB*NM blocks; decode: xcd=id&7 owns bm in [xcd*(NM/8), ...): same-bm blocks (which
// share the A panel) land on ONE XCD -> A panel L2-resident per XCD (T1). Requires NM%8==0.
template <bool OUT_BF16, bool RES>
__global__ __launch_bounds__(256) void mfma_nt(const unsigned short* __restrict__ A,
                                               const unsigned short* __restrict__ B,
                                               float* __restrict__ Cf,
                                               unsigned short* __restrict__ Cb,
                                               const float* __restrict__ res,
                                               int M, int N, int K, int bshift, int nb) {
  __shared__ unsigned short As[2][128 * 64];
  __shared__ unsigned short Bs[2][128 * 64];
  const int t = threadIdx.x;
  const int lane = t & 63, w = t >> 6;
  const int wm = w >> 1, wn = w & 1;
  const int id = blockIdx.x;
  const int nm8 = (M >> 7) >> 3;               // bm-values per XCD
  const int bm = (id & 7) * nm8 + ((id >> 3) % nm8);
  const int bn = (id >> 3) / nm8;
  (void)nb;
  const int l15 = lane & 15, l4 = lane >> 4;
  f4v acc[4][4] = {};
  const int srow = w * 32 + (lane >> 3);
  const int scol = ((lane & 7) ^ (lane >> 3)) * 8;   // pre-swizzled source col (elems)
  const unsigned short* ga = A + (size_t)(bm * 128 + srow) * K + scol;
  const unsigned short* gb = B + (size_t)(bm >> bshift) * ((size_t)N * K) +
                             (size_t)(bn * 128 + srow) * K + scol;
  const int NITER = K >> 6;
#pragma unroll
  for (int j = 0; j < 4; ++j) {
    gload16(ga + (size_t)j * 8 * K, &As[0][w * 2048 + j * 512]);
    gload16(gb + (size_t)j * 8 * K, &Bs[0][w * 2048 + j * 512]);
  }
  for (int it = 0; it < NITER; ++it) {
    const int cur = it & 1;
    if (it + 1 < NITER) {
      const int k0 = (it + 1) * 64;
      unsigned short* const nA = &As[cur ^ 1][w * 2048];
      unsigned short* const nB = &Bs[cur ^ 1][w * 2048];
#pragma unroll
      for (int j = 0; j < 4; ++j) {
        gload16(ga + (size_t)j * 8 * K + k0, nA + j * 512);
        gload16(gb + (size_t)j * 8 * K + k0, nB + j * 512);
      }
      VMCNT(8);           // own tile-it loads landed; next tile's 8 stay in flight
    } else {
      VMCNT(0);
    }
    BAR();                // all waves' tile-it loads landed
#pragma unroll
    for (int ks = 0; ks < 2; ++ks) {
      s8v af[4], bf[4];
      const int sc = (ks * 32 + l4 * 8) ^ ((l15 & 7) * 8);
#pragma unroll
      for (int i = 0; i < 4; ++i) {
        af[i] = *reinterpret_cast<const s8v*>(&As[cur][(wm * 64 + i * 16 + l15) * 64 + sc]);
        bf[i] = *reinterpret_cast<const s8v*>(&Bs[cur][(wn * 64 + i * 16 + l15) * 64 + sc]);
      }
#pragma unroll
      for (int i = 0; i < 4; ++i)
#pragma unroll
        for (int j = 0; j < 4; ++j) acc[i][j] = mfma16(af[i], bf[j], acc[i][j]);
    }
    BAR();                // compute done before buf[cur] is overwritten next iter
  }
#pragma unroll
  for (int i = 0; i < 4; ++i) {
#pragma unroll
    for (int j = 0; j < 4; ++j) {
#pragma unroll
      for (int r = 0; r < 4; ++r) {
        const int row = bm * 128 + wm * 64 + i * 16 + l4 * 4 + r;
        const int col = bn * 128 + wn * 64 + j * 16 + l15;
        float v = acc[i][j][r];
        if constexpr (RES) v += res[(size_t)row * N + col];
        if constexpr (OUT_BF16) Cb[(size_t)row * N + col] = f2bf(v);
        else Cf[(size_t)row * N + col] = v;
      }
    }
  }
}

// ---------------- weighted sum over experts (bf16 ap) -> bf16 outputs ----------------
__global__ __launch_bounds__(128) void wsum_kernel(const unsigned short* __restrict__ ap,
                                                   const float* __restrict__ w0,
                                                   const float* __restrict__ w1,
                                                   const float* __restrict__ w2,
                                                   unsigned short* __restrict__ o0,
                                                   unsigned short* __restrict__ o1,
                                                   unsigned short* __restrict__ o2,
                                                   float scale) {
  const int row = blockIdx.x, r = threadIdx.x;
  float wa[16], wb[16], wc[16];
#pragma unroll
  for (int n = 0; n < 16; ++n) wa[n] = w0[(size_t)row * NCMP + n];
  if (w1) {
#pragma unroll
    for (int n = 0; n < 16; ++n) wb[n] = w1[(size_t)row * NCMP + n];
  }
  if (w2) {
#pragma unroll
    for (int n = 0; n < 16; ++n) wc[n] = w2[(size_t)row * NCMP + n];
  }
  float a0 = 0.f, a1 = 0.f, a2 = 0.f;
  const unsigned short* apr = ap + (size_t)row * (NCMP * RANK) + r;
#pragma unroll
  for (int n = 0; n < 16; ++n) {
    const float v = bf2f(apr[n * RANK]);
    a0 += v * wa[n];
    if (w1) a1 += v * wb[n];
    if (w2) a2 += v * wc[n];
  }
  o0[(size_t)row * RANK + r] = f2bf(a0 * scale);
  if (o1) o1[(size_t)row * RANK + r] = f2bf(a1 * scale);
  if (o2) o2[(size_t)row * RANK + r] = f2bf(a2 * scale);
}

// ---------------- flash attention: frag-major gload_lds, counted vmcnt, causal ----------------
// 1D grid 1024; XCD-clustered: 8 heads per XCD x 16 qt -> each head's K/V L2-resident (T1).
__global__ __launch_bounds__(256) void flash_kernel(const unsigned short* __restrict__ Q,
                                                    const unsigned short* __restrict__ K,
                                                    const unsigned short* __restrict__ Vt,
                                                    unsigned short* __restrict__ O) {
  __shared__ unsigned short Qs[8 * 512];
  __shared__ unsigned short Ks[2][8 * 512];
  __shared__ unsigned short Vs[2][8 * 512];
  __shared__ unsigned short Ps[64 * 72];
  const int id = blockIdx.x;
  const int bh = (id & 7) * 8 + ((id >> 3) & 7);
  const int qt = id >> 6;
  const int b = bh >> 4, hh = bh & 15;
  const int base = b * 1024, q0 = qt * 64, col = hh * 64;
  const int t = threadIdx.x;
  const int lane = t & 63, w = t >> 6;
  const int l15 = lane & 15, l4 = lane >> 4;
  const unsigned short* Vh = Vt + (size_t)bh * 64 * 1024;   // [d][s]
#pragma unroll
  for (int j = 0; j < 2; ++j)
    gload16(&Q[(size_t)(base + q0 + w * 16 + l15) * DM + col + j * 32 + l4 * 8],
            Qs + (2 * w + j) * 512);
#pragma unroll
  for (int j = 0; j < 2; ++j) {
    gload16(&K[(size_t)(base + w * 16 + l15) * DM + col + j * 32 + l4 * 8],
            Ks[0] + (2 * w + j) * 512);
    gload16(&Vh[(size_t)(w * 16 + l15) * 1024 + j * 32 + l4 * 8],
            Vs[0] + (2 * w + j) * 512);
  }
  float m_r[4], l_r[4];
  f4v o[4] = {};
#pragma unroll
  for (int r = 0; r < 4; ++r) { m_r[r] = NEG_BIG; l_r[r] = 0.f; }
  for (int kt = 0; kt <= qt; ++kt) {
    const int cur = kt & 1;
    if (kt < qt) {
      const int kn = (kt + 1) * 64;
#pragma unroll
      for (int j = 0; j < 2; ++j) {
        gload16(&K[(size_t)(base + kn + w * 16 + l15) * DM + col + j * 32 + l4 * 8],
                Ks[cur ^ 1] + (2 * w + j) * 512);
        gload16(&Vh[(size_t)(w * 16 + l15) * 1024 + kn + j * 32 + l4 * 8],
                Vs[cur ^ 1] + (2 * w + j) * 512);
      }
      VMCNT(4);           // own current-tile loads landed; next tile's 4 in flight
    } else {
      VMCNT(0);
    }
    BAR();                // all waves' current-tile loads landed
    const int k0 = kt * 64;
    f4v s[4] = {};
#pragma unroll
    for (int ks = 0; ks < 2; ++ks) {
      s8v a = *reinterpret_cast<const s8v*>(&Qs[(2 * w + ks) * 512 + lane * 8]);
#pragma unroll
      for (int nj = 0; nj < 4; ++nj) {
        s8v bb = *reinterpret_cast<const s8v*>(&Ks[cur][(2 * nj + ks) * 512 + lane * 8]);
        s[nj] = mfma16(a, bb, s[nj]);
      }
    }
#pragma unroll
    for (int r = 0; r < 4; ++r) {
      const int grow = q0 + w * 16 + l4 * 4 + r;
      float sv[4];
#pragma unroll
      for (int nj = 0; nj < 4; ++nj) {
        const float xx = s[nj][r] * 0.125f;
        const int gcol = k0 + nj * 16 + l15;
        sv[nj] = (gcol <= grow) ? xx : NEG_BIG;
      }
      float mt = fmaxf(fmaxf(sv[0], sv[1]), fmaxf(sv[2], sv[3]));
#pragma unroll
      for (int msk = 1; msk < 16; msk <<= 1) mt = fmaxf(mt, __shfl_xor(mt, msk));
      const float mn = fmaxf(m_r[r], mt);
      const float sc = __expf(m_r[r] - mn);
      m_r[r] = mn;
      float rs = 0.f, pv[4];
#pragma unroll
      for (int nj = 0; nj < 4; ++nj) { pv[nj] = __expf(sv[nj] - mn); rs += pv[nj]; }
#pragma unroll
      for (int msk = 1; msk < 16; msk <<= 1) rs += __shfl_xor(rs, msk);
      l_r[r] = l_r[r] * sc + rs;
#pragma unroll
      for (int nd = 0; nd < 4; ++nd) o[nd][r] *= sc;
#pragma unroll
      for (int nj = 0; nj < 4; ++nj)
        Ps[(w * 16 + l4 * 4 + r) * 72 + nj * 16 + l15] = f2bf(pv[nj]);
    }
#pragma unroll
    for (int ks = 0; ks < 2; ++ks) {
      s8v pa = *reinterpret_cast<const s8v*>(&Ps[(w * 16 + l15) * 72 + ks * 32 + l4 * 8]);
#pragma unroll
      for (int nd = 0; nd < 4; ++nd) {
        s8v vb = *reinterpret_cast<const s8v*>(&Vs[cur][(2 * nd + ks) * 512 + lane * 8]);
        o[nd] = mfma16(pa, vb, o[nd]);
      }
    }
    BAR();                // reads of buf[cur] done before next iter's gloads overwrite it
  }
#pragma unroll
  for (int nd = 0; nd < 4; ++nd)
#pragma unroll
    for (int r = 0; r < 4; ++r) {
      const int grow = base + q0 + w * 16 + l4 * 4 + r;
      O[(size_t)grow * DM + col + nd * 16 + l15] = f2bf(o[nd][r] / l_r[r]);
    }
}

// ---------------- fused kscores MFMA GEMM + branchless in-register per-row top-8 ----------------
__global__ __launch_bounds__(256) void topk_kernel(const unsigned short* __restrict__ Qm,
                                                   const unsigned short* __restrict__ kK,
                                                   float* __restrict__ tks,
                                                   int* __restrict__ tki) {
  __shared__ __align__(16) char arena[32768];    // 4 x 8KB frag-major K buffers
  unsigned short* const K0 = (unsigned short*)arena;
  unsigned short* const K1 = (unsigned short*)(arena + 8192);
  unsigned short* const K2 = (unsigned short*)(arena + 16384);
  unsigned short* const K3 = (unsigned short*)(arena + 24576);
  const int id = blockIdx.x;
  const int sp = (id & 7) * 4 + ((id >> 3) & 3);   // XCD id%8 covers 4 sp-slices (2MB, L2-fits)
  const int rb = id >> 5;
  const int r0 = rb * 64, kb0 = sp * TK_KEYS;
  const int t = threadIdx.x;
  const int lane = t & 63, w = t >> 6;
  const int l15 = lane & 15, l4 = lane >> 4;
  s8v qf[4];
#pragma unroll
  for (int ks = 0; ks < 4; ++ks)
    qf[ks] = *reinterpret_cast<const s8v*>(
        &Qm[(size_t)(r0 + w * 16 + l15) * RANK + ks * 32 + l4 * 8]);
  unsigned bs0 = 0u, bs1 = 0u, bs2 = 0u, bs3 = 0u, bs4 = 0u, bs5 = 0u, bs6 = 0u, bs7 = 0u;
  const int s0i = 2 * w, s1i = 2 * w + 1;
  const unsigned short* g0 = kK + (size_t)(kb0 + (s0i >> 2) * 16 + l15) * RANK + (s0i & 3) * 32 + l4 * 8;
  const unsigned short* g1 = kK + (size_t)(kb0 + (s1i >> 2) * 16 + l15) * RANK + (s1i & 3) * 32 + l4 * 8;
  gload16(g0, K0 + s0i * 512);
  gload16(g1, K0 + s1i * 512);

#define TK_STEP(BC, BN, CH)                                                        \
  {                                                                                \
    if ((CH) + 1 < 32) {                                                           \
      const size_t off_ = (size_t)((CH) + 1) * 32 * RANK;                          \
      gload16(g0 + off_, (BN) + s0i * 512);                                        \
      gload16(g1 + off_, (BN) + s1i * 512);                                        \
      VMCNT(2);                                                                    \
    } else {                                                                       \
      VMCNT(0);                                                                    \
    }                                                                              \
    BAR();                                                                         \
    f4v a0_ = f4v{4.f, 4.f, 4.f, 4.f};                                             \
    f4v a1_ = f4v{4.f, 4.f, 4.f, 4.f};                                             \
    __builtin_amdgcn_s_setprio(1);                                                 \
    _Pragma("unroll")                                                              \
    for (int ks_ = 0; ks_ < 4; ++ks_) {                                            \
      a0_ = mfma16(*reinterpret_cast<const s8v*>(&(BC)[ks_ * 512 + lane * 8]),     \
                   qf[ks_], a0_);                                                  \
      a1_ = mfma16(*reinterpret_cast<const s8v*>(&(BC)[(4 + ks_) * 512 + lane * 8]),\
                   qf[ks_], a1_);                                                  \
    }                                                                              \
    __builtin_amdgcn_s_setprio(0);                                                 \
    const unsigned ivb_ = 2047u - (unsigned)((CH) * 32 + l4 * 4);                  \
    _Pragma("unroll")                                                              \
    for (int r_ = 0; r_ < 4; ++r_) {                                               \
      const unsigned u_ = __float_as_uint(a0_[r_]);                                \
      const unsigned pk_ = (u_ & 0xFFFFF800u) | (ivb_ - (unsigned)r_);             \
      bs7 = umed3(bs6, pk_, bs7); bs6 = umed3(bs5, pk_, bs6);                      \
      bs5 = umed3(bs4, pk_, bs5); bs4 = umed3(bs3, pk_, bs4);                      \
      bs3 = umed3(bs2, pk_, bs3); bs2 = umed3(bs1, pk_, bs2);                      \
      bs1 = umed3(bs0, pk_, bs1); bs0 = max(bs0, pk_);                             \
    }                                                                              \
    _Pragma("unroll")                                                              \
    for (int r_ = 0; r_ < 4; ++r_) {                                               \
      const unsigned u_ = __float_as_uint(a1_[r_]);                                \
      const unsigned pk_ = (u_ & 0xFFFFF800u) | (ivb_ - (unsigned)(16 + r_));      \
      bs7 = umed3(bs6, pk_, bs7); bs6 = umed3(bs5, pk_, bs6);                      \
      bs5 = umed3(bs4, pk_, bs5); bs4 = umed3(bs3, pk_, bs4);                      \
      bs3 = umed3(bs2, pk_, bs3); bs2 = umed3(bs1, pk_, bs2);                      \
      bs1 = umed3(bs0, pk_, bs1); bs0 = max(bs0, pk_);                             \
    }                                                                              \
  }

  for (int c4 = 0; c4 < 32; c4 += 4) {
    TK_STEP(K0, K1, c4 + 0);
    TK_STEP(K1, K2, c4 + 1);
    TK_STEP(K2, K3, c4 + 2);
    TK_STEP(K3, K0, c4 + 3);
  }
#undef TK_STEP

  unsigned* const M = (unsigned*)arena;   // [64][33] (overlaps K0/K1; last reads >=2 barriers back)
  const int row = w * 16 + l15;
  {
    unsigned* mp = M + row * 33 + l4 * 8;
    mp[0] = bs0; mp[1] = bs1; mp[2] = bs2; mp[3] = bs3;
    mp[4] = bs4; mp[5] = bs5; mp[6] = bs6; mp[7] = bs7;
  }
  __syncthreads();
  if (t < 64) {
    const unsigned* mr = M + t * 33;
    int h0 = 0, h1 = 0, h2 = 0, h3 = 0;
    const size_t oo = ((size_t)sp * NROWS + r0 + t) * TOPK;
    for (int k = 0; k < TOPK; ++k) {
      const unsigned c0 = (h0 < 8) ? mr[0 + h0] : 0u;
      const unsigned c1 = (h1 < 8) ? mr[8 + h1] : 0u;
      const unsigned c2 = (h2 < 8) ? mr[16 + h2] : 0u;
      const unsigned c3 = (h3 < 8) ? mr[24 + h3] : 0u;
      const unsigned m01 = (c0 >= c1) ? c0 : c1; const int l01 = (c0 >= c1) ? 0 : 1;
      const unsigned m23 = (c2 >= c3) ? c2 : c3; const int l23 = (c2 >= c3) ? 2 : 3;
      const unsigned bst = (m01 >= m23) ? m01 : m23;
      const int bl = (m01 >= m23) ? l01 : l23;
      tks[oo + k] = __uint_as_float(bst & 0xFFFFF800u) - 4.0f;   // un-bias
      tki[oo + k] = kb0 + 2047 - (int)(bst & 0x7FFu);
      h0 += (bl == 0); h1 += (bl == 1); h2 += (bl == 2); h3 += (bl == 3);
    }
  }
}

// ---------------- merge splits (parallel rank-select), softmax, gather, out += mem ----------------
__global__ __launch_bounds__(256) void gather_kernel(const float* __restrict__ tks,
                                                     const int* __restrict__ tki,
                                                     const float* __restrict__ kV,
                                                     float* __restrict__ out) {
  __shared__ float ls[TK_SPLIT * TOPK];
  __shared__ int li[TK_SPLIT * TOPK];
  __shared__ float selv[TOPK];
  __shared__ int seli[TOPK];
  __shared__ float wsel[TOPK];
  const int row = blockIdx.x, t = threadIdx.x;
  if (t < TK_SPLIT * TOPK) {
    const int l = t >> 3, k = t & 7;
    ls[t] = tks[((size_t)l * NROWS + row) * TOPK + k];
    li[t] = tki[((size_t)l * NROWS + row) * TOPK + k];
  }
  __syncthreads();
  if (t < TK_SPLIT * TOPK) {
    const float v = ls[t];
    const int myid = li[t];
    int rank = 0;
    for (int j = 0; j < TK_SPLIT * TOPK; ++j) {
      const float u = ls[j];
      rank += (u > v) || (u == v && li[j] < myid);
    }
    if (rank < TOPK) { selv[rank] = v; seli[rank] = myid; }
  }
  __syncthreads();
  if (t == 0) {
    const float m = selv[0];
    float sum = 0.f, e[TOPK];
#pragma unroll
    for (int k = 0; k < TOPK; ++k) { e[k] = __expf(selv[k] - m); sum += e[k]; }
    const float inv = 1.f / sum;
#pragma unroll
    for (int k = 0; k < TOPK; ++k) wsel[k] = e[k] * inv;
  }
  __syncthreads();
  float4 accv = reinterpret_cast<float4*>(out + (size_t)row * DM)[t];
#pragma unroll
  for (int k = 0; k < TOPK; ++k) {
    const float4 v4 = reinterpret_cast<const float4*>(kV + (size_t)seli[k] * DM)[t];
    const float wk = wsel[k];
    accv.x += wk * v4.x; accv.y += wk * v4.y; accv.z += wk * v4.z; accv.w += wk * v4.w;
  }
  reinterpret_cast<float4*>(out + (size_t)row * DM)[t] = accv;
}

extern "C" void kernel_launch(void* const* d_in, const int* in_sizes, int n_in,
                              void* d_out, int out_size, void* d_ws, size_t ws_size,
                              hipStream_t stream) {
  (void)in_sizes; (void)n_in; (void)out_size; (void)ws_size;
  const float* x    = (const float*)d_in[0];
  const float* neur = (const float*)d_in[2];
  const float* kK   = (const float*)d_in[3];
  const float* kV   = (const float*)d_in[4];
  const float* rQ   = (const float*)d_in[5];
  const float* rK   = (const float*)d_in[6];
  const float* rV   = (const float*)d_in[7];
  const float* rM   = (const float*)d_in[8];
  const float* WQ   = (const float*)d_in[9];
  const float* WK   = (const float*)d_in[10];
  const float* WV   = (const float*)d_in[11];
  const float* WO   = (const float*)d_in[12];
  const float* g1   = (const float*)d_in[13];
  const float* b1   = (const float*)d_in[14];
  const float* g2   = (const float*)d_in[15];
  const float* b2   = (const float*)d_in[16];
  float* out = (float*)d_out;

  char* base = (char*)d_ws;
  auto alloc = [&](size_t bytes) { char* r = base; base += (bytes + 255) & ~(size_t)255; return r; };
  unsigned short* hbf   = (unsigned short*)alloc((size_t)NROWS * DM * 2);   // h bf16; reused attn_bf
  unsigned short* apb   = (unsigned short*)alloc((size_t)3 * NROWS * DM * 2); // ap bf16 / QKV bf16
  unsigned short* neurT = (unsigned short*)alloc((size_t)NCMP * RANK * DM * 2);
  unsigned short* WQKVt = (unsigned short*)alloc((size_t)3 * DM * RANK * 2);
  unsigned short* WOt   = (unsigned short*)alloc((size_t)DM * DM * 2);
  unsigned short* kKb   = (unsigned short*)alloc((size_t)NKNOW * RANK * 2);
  unsigned short* rTb   = (unsigned short*)alloc((size_t)128 * DM * 2);     // routersT [128][1024]
  unsigned short* hQKVb = (unsigned short*)alloc((size_t)3 * NROWS * RANK * 2);
  unsigned short* Qmb   = (unsigned short*)alloc((size_t)NROWS * RANK * 2);
  unsigned short* Vtb   = (unsigned short*)alloc((size_t)NROWS * DM * 2);   // V per-head transposed
  float* scores = (float*)alloc((size_t)NROWS * 128 * 4);                   // router scores
  float* wQw = (float*)alloc((size_t)NROWS * NCMP * 4);
  float* wKw = (float*)alloc((size_t)NROWS * NCMP * 4);
  float* wVw = (float*)alloc((size_t)NROWS * NCMP * 4);
  float* wMw = (float*)alloc((size_t)NROWS * NCMP * 4);
  float* tks = (float*)alloc((size_t)TK_SPLIT * NROWS * TOPK * 4);
  int*   tki = (int*)alloc((size_t)TK_SPLIT * NROWS * TOPK * 4);
  unsigned short* Qb = apb;                 // [3][4096][1024] bf16 (after wsum consumes ap)
  unsigned short* Kb = Qb + (size_t)NROWS * DM;
  unsigned short* Vb = Kb + (size_t)NROWS * DM;
  unsigned short* attnb = hbf;
  unsigned short* hQb = hQKVb;
  unsigned short* hKb = hQKVb + (size_t)NROWS * RANK;
  unsigned short* hVb = hQKVb + (size_t)2 * NROWS * RANK;

  // one-time weight converts, single launch
  prep_kernel<<<5584, 256, 0, stream>>>(kK, kKb, neur, neurT, WQ, WK, WV, WQKVt, WO, WOt,
                                        rQ, rK, rV, rM, rTb);

  // ---- attention half ----
  ln_kernel<<<NROWS, 256, 0, stream>>>(x, g1, b1, hbf);
  mfma_nt<true, false><<<512, 256, 0, stream>>>(hbf, neurT, nullptr, apb, nullptr,
                                                NROWS, NCMP * RANK, DM, 30, 16);
  // router scores via MFMA: scores[4096][128] = h @ routersT^T (groups: rQ,rK,rV,rM,pad)
  mfma_nt<false, false><<<32, 256, 0, stream>>>(hbf, rTb, scores, nullptr, nullptr,
                                                NROWS, 128, DM, 30, 1);
  softmax16_kernel<<<NROWS, 64, 0, stream>>>(scores, wQw, wKw, wVw, nullptr);
  wsum_kernel<<<NROWS, 128, 0, stream>>>(apb, wQw, wKw, wVw, hQb, hKb, hVb, 1.0f);
  // batched QKV projection: A=[3*4096][128], B switches every 32 row-tiles
  mfma_nt<true, false><<<768, 256, 0, stream>>>(hQKVb, WQKVt, nullptr, Qb, nullptr,
                                                3 * NROWS, DM, RANK, 5, 8);
  vtr_kernel<<<dim3(32, 2, 64), 256, 0, stream>>>(Vb, Vtb);
  flash_kernel<<<1024, 256, 0, stream>>>(Qb, Kb, Vtb, attnb);
  mfma_nt<false, true><<<256, 256, 0, stream>>>(attnb, WOt, out, nullptr, x,
                                                NROWS, DM, DM, 30, 8);

  // ---- knowledge-memory half ----
  ln_kernel<<<NROWS, 256, 0, stream>>>(out, g2, b2, hbf);
  mfma_nt<true, false><<<512, 256, 0, stream>>>(hbf, neurT, nullptr, apb, nullptr,
                                                NROWS, NCMP * RANK, DM, 30, 16);
  mfma_nt<false, false><<<32, 256, 0, stream>>>(hbf, rTb, scores, nullptr, nullptr,
                                                NROWS, 128, DM, 30, 1);
  softmax16_kernel<<<NROWS, 64, 0, stream>>>(scores, nullptr, nullptr, nullptr, wMw);
  wsum_kernel<<<NROWS, 128, 0, stream>>>(apb, wMw, nullptr, nullptr, Qmb, nullptr, nullptr,
                                         0.08838834764831845f /* 1/sqrt(128) */);
  topk_kernel<<<2048, 256, 0, stream>>>(Qmb, kKb, tks, tki);
  gather_kernel<<<NROWS, 256, 0, stream>>>(tks, tki, kV, out);
}